// Round 4
// baseline (1167.926 us; speedup 1.0000x reference)
//
#include <hip/hip_runtime.h>

#define Bq   16
#define Sq   512
#define Vq   128
#define NCq  10000

typedef __attribute__((ext_vector_type(8))) short short8v;
typedef __attribute__((ext_vector_type(4))) float f32x4;

// ---- workspace layout (float offsets) ----
#define OFF_XP     0u          // [512 t][96 r4][16 b][4]  xp + biases + r*wvr folded
#define OFF_PRE1   3145728u    // [8192 m][128 j]          pre1 + b1 + r*wvr1 folded
#define OFF_WTIH   4194304u    // [128 k][384 g]           W_ih[:, :V] transposed
#define OFF_WVRIH  4243456u    // [384]  v_r @ W_ih[:, V:2V].T
#define OFF_WVR1   4243840u    // [128]  v_r @ m2_W1[2V:3V, :]
#define OFF_WVB    4243968u    // [128]  v_beta @ m2_W1[0:V, :]
#define OFF_PO     4244096u    // int [512 t][16 b] prev occurrence (-1 if none)

__device__ __forceinline__ unsigned short f2bf(float x) {
    unsigned u = __builtin_bit_cast(unsigned, x);
    unsigned r = (u + 0x7fffu + ((u >> 16) & 1u)) >> 16;
    return (unsigned short)r;
}
__device__ __forceinline__ float bf2f(unsigned short h) {
    return __builtin_bit_cast(float, ((unsigned)h) << 16);
}

// ============ K0: transpose, small vectors, prev-occurrence, gamma ============
__global__ __launch_bounds__(256) void k0_prep(
    const int* __restrict__ c_seq, const int* __restrict__ d_seq,
    const float* __restrict__ D1_w,
    const float* __restrict__ W_ih,
    const float* __restrict__ v_r, const float* __restrict__ v_beta,
    const float* __restrict__ m2W1,
    float* __restrict__ ws, float* __restrict__ gamma_out)
{
    const int blk = blockIdx.x, tid = threadIdx.x;

    if (blk < 128) {
        float* WTIH = ws + OFF_WTIH;
        int base = blk * 384;
        for (int i = tid; i < 384; i += 256) {
            int e = base + i;
            int k = e / 384, g = e % 384;
            WTIH[e] = W_ih[g * 256 + k];
        }
    } else if (blk == 128) {
        float* WVRIH = ws + OFF_WVRIH;
        float* WVR1  = ws + OFF_WVR1;
        float* WVB   = ws + OFF_WVB;
        for (int g = tid; g < 384; g += 256) {
            float a = 0.f;
            for (int k = 0; k < 128; ++k) a = fmaf(v_r[k], W_ih[g * 256 + 128 + k], a);
            WVRIH[g] = a;
        }
        if (tid < 128) {
            float a = 0.f, b = 0.f;
            for (int k = 0; k < 128; ++k) {
                a = fmaf(v_r[k],    m2W1[(256 + k) * 128 + tid], a);
                b = fmaf(v_beta[k], m2W1[k * 128 + tid],         b);
            }
            WVR1[tid] = a; WVB[tid] = b;
        }
    } else if (blk < 145) {
        const int b = blk - 129;
        __shared__ int cs[Sq];
        for (int i = tid; i < Sq; i += 256) cs[i] = c_seq[b * Sq + i];
        __syncthreads();
        int* PO = (int*)(ws + OFF_PO);
        for (int t = tid; t < Sq; t += 256) {
            int c = cs[t];
            int po = -1;
            for (int u = t - 1; u >= 0; --u) if (cs[u] == c) { po = u; break; }
            PO[t * 16 + b] = po;
        }
    } else {
        const int b = blk - 145;
        for (int s = tid; s < Sq; s += 256)
            gamma_out[b * Sq + s] = D1_w[d_seq[b * Sq + s]];
    }
}

// ============ K1: batched GEMM [8192,128]x[128,512] -> xp4 | pre1 (biases folded) ============
__global__ __launch_bounds__(256) void k1_gemm(
    const int* __restrict__ d_seq, const float* __restrict__ D2_w,
    const float* __restrict__ m2W1,
    const float* __restrict__ b_ih, const float* __restrict__ b_hh,
    const float* __restrict__ r_seq, const float* __restrict__ m2b1,
    float* __restrict__ ws)
{
    __shared__ float As[64 * 128];   // [r][k]
    __shared__ float Bs[128 * 64];   // [k][c]
    const int blk = blockIdx.x, tid = threadIdx.x;
    const int nc = blk & 7;
    const int m0 = (blk >> 3) * 64;
    const float* WTIH = ws + OFF_WTIH;

    const float4* D2v = (const float4*)D2_w;
    for (int e = tid; e < 2048; e += 256) {
        int r = e >> 5, q = e & 31;
        int d = d_seq[m0 + r];
        *(float4*)&As[r * 128 + 4 * q] = D2v[d * 32 + q];
    }
    for (int e = tid; e < 2048; e += 256) {
        int k = e >> 4, q = e & 15;
        float4 v;
        if (nc < 6) v = *(const float4*)&WTIH[k * 384 + nc * 64 + 4 * q];
        else        v = *(const float4*)&m2W1[(128 + k) * 128 + (nc - 6) * 64 + 4 * q];
        *(float4*)&Bs[k * 64 + 4 * q] = v;
    }
    __syncthreads();

    const int tx = tid & 15, ty = tid >> 4;
    const int c0 = 4 * tx, r0 = 4 * ty;
    float acc[4][4];
#pragma unroll
    for (int i = 0; i < 4; ++i)
#pragma unroll
        for (int j = 0; j < 4; ++j) acc[i][j] = 0.f;

    for (int k = 0; k < 128; ++k) {
        float4 bv = *(const float4*)&Bs[k * 64 + c0];
#pragma unroll
        for (int i = 0; i < 4; ++i) {
            float a = As[(r0 + i) * 128 + k];
            acc[i][0] = fmaf(a, bv.x, acc[i][0]);
            acc[i][1] = fmaf(a, bv.y, acc[i][1]);
            acc[i][2] = fmaf(a, bv.z, acc[i][2]);
            acc[i][3] = fmaf(a, bv.w, acc[i][3]);
        }
    }

    float rsv[4];
#pragma unroll
    for (int i = 0; i < 4; ++i) rsv[i] = r_seq[m0 + r0 + i];

    if (nc < 6) {
        const int grow0 = nc * 64 + c0;
        float4 bi  = *(const float4*)&b_ih[grow0];
        float4 wv4 = *(const float4*)&(ws + OFF_WVRIH)[grow0];
        float4 bh4 = make_float4(0.f, 0.f, 0.f, 0.f);
        if (nc < 4) bh4 = *(const float4*)&b_hh[grow0];   // r,z gates get b_hh folded
        float* XP4 = ws + OFF_XP;
        const int r4 = grow0 >> 2;
#pragma unroll
        for (int i = 0; i < 4; ++i) {
            int row = m0 + r0 + i;
            int t = row & 511, bb = row >> 9;
            float4 v;
            v.x = acc[i][0] + bi.x + bh4.x + rsv[i] * wv4.x;
            v.y = acc[i][1] + bi.y + bh4.y + rsv[i] * wv4.y;
            v.z = acc[i][2] + bi.z + bh4.z + rsv[i] * wv4.z;
            v.w = acc[i][3] + bi.w + bh4.w + rsv[i] * wv4.w;
            *(float4*)&XP4[((t * 96 + r4) * 16 + bb) * 4] = v;
        }
    } else {
        const int j0 = (nc - 6) * 64 + c0;
        float4 b1v = *(const float4*)&m2b1[j0];
        float4 wr1 = *(const float4*)&(ws + OFF_WVR1)[j0];
        float* PRE1 = ws + OFF_PRE1;
#pragma unroll
        for (int i = 0; i < 4; ++i) {
            int row = m0 + r0 + i;
            float4 v;
            v.x = acc[i][0] + b1v.x + rsv[i] * wr1.x;
            v.y = acc[i][1] + b1v.y + rsv[i] * wr1.y;
            v.z = acc[i][2] + b1v.z + rsv[i] * wr1.z;
            v.w = acc[i][3] + b1v.w + rsv[i] * wr1.w;
            *(float4*)&PRE1[(size_t)row * 128 + j0] = v;
        }
    }
}

// ============ K2: MFMA scans. block 0: GRU (all 16 batches). block 1: beta (all 16) ============
// GRU:  h' per step via v_mfma_f32_16x16x32_bf16, W_hh hi/lo in registers (A),
//       h hi/lo bf16 planes in LDS (B, [b][k] stride 136), C accumulates fp32.
// beta: same structure with W2 (M=128).
#define PLN 136          // bf16 plane stride (padded)
#define PLSZ (16*PLN+8)  // ushorts per plane

__global__ __launch_bounds__(256, 1) void k2_scan(
    const float* __restrict__ W_hh, const float* __restrict__ b_hh,
    const float* __restrict__ m2W2, const float* __restrict__ m2b2,
    const float* __restrict__ m2W3, const float* __restrict__ m2b3,
    float* __restrict__ ws,
    float* __restrict__ hseq_out, float* __restrict__ beta_out)
{
    __shared__ __align__(16) unsigned char smem[74560];
    const int tid = threadIdx.x;
    const int l = tid & 63, wv = tid >> 6;
    const int qq = l >> 4, cb = l & 15;

    if (blockIdx.x == 0) {
        // ---------------- GRU, batches 0..15, one block ----------------
        unsigned short* hHI = (unsigned short*)smem;                 // [2][PLSZ]
        unsigned short* hLO = (unsigned short*)(smem + 4 * PLSZ);    // [2][PLSZ] (2B each)
        // actually: hHI buffers at 0 and PLSZ; hLO at 2*PLSZ, 3*PLSZ (ushort units)
        // A-fragments: W_hh bf16 hi/lo, 6 tiles x 4 kfrags
        short8v aHI[6][4], aLO[6][4];
#pragma unroll
        for (int tau = 0; tau < 6; ++tau) {
            const int grow = (tau >> 1) * 128 + 32 * wv + (tau & 1) * 16 + cb;
            const float* wrow = W_hh + grow * 128;
#pragma unroll
            for (int kf = 0; kf < 4; ++kf) {
                short8v hi, lo;
#pragma unroll
                for (int e = 0; e < 8; ++e) {
                    float x = wrow[kf * 32 + qq * 8 + e];
                    unsigned short hb = f2bf(x);
                    unsigned short lb = f2bf(x - bf2f(hb));
                    hi[e] = (short)hb; lo[e] = (short)lb;
                }
                aHI[tau][kf] = hi; aLO[tau][kf] = lo;
            }
        }
        float bhhn[2][4];
#pragma unroll
        for (int jh = 0; jh < 2; ++jh)
#pragma unroll
            for (int i = 0; i < 4; ++i)
                bhhn[jh][i] = b_hh[256 + 32 * wv + 16 * jh + qq * 4 + i];

        const float* XP4 = ws + OFF_XP;
        float4 px[6];
#pragma unroll
        for (int tau = 0; tau < 6; ++tau) {
            const int r4 = (tau >> 1) * 32 + 8 * wv + (tau & 1) * 4 + qq;
            px[tau] = *(const float4*)&XP4[(r4 * 16 + cb) * 4];
        }
        float hold[2][4];
#pragma unroll
        for (int jh = 0; jh < 2; ++jh)
#pragma unroll
            for (int i = 0; i < 4; ++i) hold[jh][i] = 0.f;

        for (int i = tid; i < 2 * PLSZ; i += 256) { hHI[i] = 0; hLO[i] = 0; }
        __syncthreads();

        for (int t = 0; t < 512; ++t) {
            const unsigned short* HI = hHI + (t & 1) * PLSZ;
            const unsigned short* LO = hLO + (t & 1) * PLSZ;
            unsigned short* HIn = hHI + ((t + 1) & 1) * PLSZ;
            unsigned short* LOn = hLO + ((t + 1) & 1) * PLSZ;

            f32x4 C[6];
#pragma unroll
            for (int tau = 0; tau < 6; ++tau) { C[tau] = (f32x4){0.f, 0.f, 0.f, 0.f}; }
#pragma unroll
            for (int kf = 0; kf < 4; ++kf) {
                short8v Bh = *(const short8v*)(HI + cb * PLN + kf * 32 + qq * 8);
                short8v Bl = *(const short8v*)(LO + cb * PLN + kf * 32 + qq * 8);
#pragma unroll
                for (int tau = 0; tau < 6; ++tau) {
                    C[tau] = __builtin_amdgcn_mfma_f32_16x16x32_bf16(aHI[tau][kf], Bh, C[tau], 0, 0, 0);
                    C[tau] = __builtin_amdgcn_mfma_f32_16x16x32_bf16(aHI[tau][kf], Bl, C[tau], 0, 0, 0);
                    C[tau] = __builtin_amdgcn_mfma_f32_16x16x32_bf16(aLO[tau][kf], Bh, C[tau], 0, 0, 0);
                }
            }
            // prefetch next-step pre-activations
            float4 pxn[6];
            if (t < 511) {
#pragma unroll
                for (int tau = 0; tau < 6; ++tau) {
                    const int r4 = (tau >> 1) * 32 + 8 * wv + (tau & 1) * 4 + qq;
                    pxn[tau] = *(const float4*)&XP4[(((t + 1) * 96 + r4) * 16 + cb) * 4];
                }
            }
            // gates in C-fragment layout: row j = 32w+16jh+4q+i, col b = cb
            float hnew[2][4];
#pragma unroll
            for (int jh = 0; jh < 2; ++jh) {
#pragma unroll
                for (int i = 0; i < 4; ++i) {
                    float pr = C[0 + jh][i] + px[0 + jh][i];
                    float pz = C[2 + jh][i] + px[2 + jh][i];
                    float r = 1.f / (1.f + __expf(-pr));
                    float z = 1.f / (1.f + __expf(-pz));
                    float hn = C[4 + jh][i] + bhhn[jh][i];
                    float npre = fmaf(r, hn, px[4 + jh][i]);
                    float ax = fabsf(npre);
                    float e2 = __expf(-2.f * ax);
                    float n = copysignf((1.f - e2) / (1.f + e2), npre);
                    float hv = (1.f - z) * n + z * hold[jh][i];
                    hold[jh][i] = hv;
                    hnew[jh][i] = hv;
                }
            }
            // store hseq (fp32) + write next bf16 hi/lo planes
#pragma unroll
            for (int jh = 0; jh < 2; ++jh) {
                *(float4*)&hseq_out[(size_t)(cb * 512 + t) * 128 + 32 * wv + 16 * jh + qq * 4] =
                    make_float4(hnew[jh][0], hnew[jh][1], hnew[jh][2], hnew[jh][3]);
                unsigned short hb0 = f2bf(hnew[jh][0]), hb1 = f2bf(hnew[jh][1]);
                unsigned short hb2 = f2bf(hnew[jh][2]), hb3 = f2bf(hnew[jh][3]);
                unsigned short lb0 = f2bf(hnew[jh][0] - bf2f(hb0));
                unsigned short lb1 = f2bf(hnew[jh][1] - bf2f(hb1));
                unsigned short lb2 = f2bf(hnew[jh][2] - bf2f(hb2));
                unsigned short lb3 = f2bf(hnew[jh][3] - bf2f(hb3));
                uint2 hw, lw;
                hw.x = (unsigned)hb0 | ((unsigned)hb1 << 16);
                hw.y = (unsigned)hb2 | ((unsigned)hb3 << 16);
                lw.x = (unsigned)lb0 | ((unsigned)lb1 << 16);
                lw.y = (unsigned)lb2 | ((unsigned)lb3 << 16);
                *(uint2*)(HIn + cb * PLN + 32 * wv + 16 * jh + qq * 4) = hw;
                *(uint2*)(LOn + cb * PLN + 32 * wv + 16 * jh + qq * 4) = lw;
            }
#pragma unroll
            for (int tau = 0; tau < 6; ++tau) px[tau] = pxn[tau];
            __syncthreads();
        }
    } else {
        // ---------------- beta scan, batches 0..15, one block ----------------
        float* bhL = (float*)smem;                                   // [16][512]
        int* poT = (int*)(smem + 32768);                             // [512][16]
        unsigned short* h1HI = (unsigned short*)(smem + 65536);      // [PLSZ]
        unsigned short* h1LO = (unsigned short*)(smem + 69904);      // [PLSZ]
        float* redL = (float*)(smem + 74272);                        // [4][16]

        // stage po table
        {
            const int* POg = (const int*)(ws + OFF_PO);
            for (int i = tid; i < 8192; i += 256) poT[i] = POg[i];
        }
        // A-fragments: W2 (M[j][k] = m2W2[k*128+j]) bf16 hi/lo, 2 tiles
        short8v aHI[2][4], aLO[2][4];
#pragma unroll
        for (int tau = 0; tau < 2; ++tau) {
            const int j = 32 * wv + 16 * tau + cb;
#pragma unroll
            for (int kf = 0; kf < 4; ++kf) {
                short8v hi, lo;
#pragma unroll
                for (int e = 0; e < 8; ++e) {
                    float x = m2W2[(kf * 32 + qq * 8 + e) * 128 + j];
                    unsigned short hb = f2bf(x);
                    unsigned short lb = f2bf(x - bf2f(hb));
                    hi[e] = (short)hb; lo[e] = (short)lb;
                }
                aHI[tau][kf] = hi; aLO[tau][kf] = lo;
            }
        }
        float w3C[2][4], b2C[2][4];
#pragma unroll
        for (int tau = 0; tau < 2; ++tau)
#pragma unroll
            for (int i = 0; i < 4; ++i) {
                w3C[tau][i] = m2W3[32 * wv + 16 * tau + qq * 4 + i];
                b2C[tau][i] = m2b2[32 * wv + 16 * tau + qq * 4 + i];
            }
        const float b3v = m2b3[0];

        // h1-compute mapping: thread -> (batch bb2, 8 consecutive j)
        const int bb2 = tid & 15, j8 = tid >> 4;
        float wvb[8];
#pragma unroll
        for (int e = 0; e < 8; ++e) wvb[e] = (ws + OFF_WVB)[j8 * 8 + e];
        const float* p1base = ws + OFF_PRE1 + (size_t)(bb2 * 512) * 128 + j8 * 8;

        float4 p1a = *(const float4*)&p1base[0];
        float4 p1b = *(const float4*)&p1base[4];
        __syncthreads();

        for (int t = 0; t < 512; ++t) {
            // phase A: h1 = relu(pre1' + bp*wvb), write bf16 planes
            int po = poT[t * 16 + bb2];
            float bp = (po >= 0) ? bhL[bb2 * 512 + po] : 0.f;
            float hv[8];
            hv[0] = fmaxf(0.f, fmaf(bp, wvb[0], p1a.x));
            hv[1] = fmaxf(0.f, fmaf(bp, wvb[1], p1a.y));
            hv[2] = fmaxf(0.f, fmaf(bp, wvb[2], p1a.z));
            hv[3] = fmaxf(0.f, fmaf(bp, wvb[3], p1a.w));
            hv[4] = fmaxf(0.f, fmaf(bp, wvb[4], p1b.x));
            hv[5] = fmaxf(0.f, fmaf(bp, wvb[5], p1b.y));
            hv[6] = fmaxf(0.f, fmaf(bp, wvb[6], p1b.z));
            hv[7] = fmaxf(0.f, fmaf(bp, wvb[7], p1b.w));
            uint4 hw, lw;
            {
                unsigned short h[8], lo[8];
#pragma unroll
                for (int e = 0; e < 8; ++e) {
                    h[e] = f2bf(hv[e]);
                    lo[e] = f2bf(hv[e] - bf2f(h[e]));
                }
                hw.x = (unsigned)h[0] | ((unsigned)h[1] << 16);
                hw.y = (unsigned)h[2] | ((unsigned)h[3] << 16);
                hw.z = (unsigned)h[4] | ((unsigned)h[5] << 16);
                hw.w = (unsigned)h[6] | ((unsigned)h[7] << 16);
                lw.x = (unsigned)lo[0] | ((unsigned)lo[1] << 16);
                lw.y = (unsigned)lo[2] | ((unsigned)lo[3] << 16);
                lw.z = (unsigned)lo[4] | ((unsigned)lo[5] << 16);
                lw.w = (unsigned)lo[6] | ((unsigned)lo[7] << 16);
            }
            *(uint4*)(h1HI + bb2 * PLN + j8 * 8) = hw;
            *(uint4*)(h1LO + bb2 * PLN + j8 * 8) = lw;
            // prefetch next pre1
            float4 p1an, p1bn;
            if (t < 511) {
                p1an = *(const float4*)&p1base[(size_t)(t + 1) * 128];
                p1bn = *(const float4*)&p1base[(size_t)(t + 1) * 128 + 4];
            }
            __syncthreads();   // barrier 1: planes ready

            // phase B: MFMA h2-pre
            f32x4 C[2];
            C[0] = (f32x4){0.f, 0.f, 0.f, 0.f};
            C[1] = (f32x4){0.f, 0.f, 0.f, 0.f};
#pragma unroll
            for (int kf = 0; kf < 4; ++kf) {
                short8v Bh = *(const short8v*)(h1HI + cb * PLN + kf * 32 + qq * 8);
                short8v Bl = *(const short8v*)(h1LO + cb * PLN + kf * 32 + qq * 8);
#pragma unroll
                for (int tau = 0; tau < 2; ++tau) {
                    C[tau] = __builtin_amdgcn_mfma_f32_16x16x32_bf16(aHI[tau][kf], Bh, C[tau], 0, 0, 0);
                    C[tau] = __builtin_amdgcn_mfma_f32_16x16x32_bf16(aHI[tau][kf], Bl, C[tau], 0, 0, 0);
                    C[tau] = __builtin_amdgcn_mfma_f32_16x16x32_bf16(aLO[tau][kf], Bh, C[tau], 0, 0, 0);
                }
            }
            // phase C: h2 relu, dot with w3, reduce over j
            float part = 0.f;
#pragma unroll
            for (int tau = 0; tau < 2; ++tau)
#pragma unroll
                for (int i = 0; i < 4; ++i) {
                    float h2 = fmaxf(0.f, C[tau][i] + b2C[tau][i]);
                    part = fmaf(h2, w3C[tau][i], part);
                }
            part += __shfl_xor(part, 16);
            part += __shfl_xor(part, 32);
            if (l < 16) redL[wv * 16 + l] = part;
            __syncthreads();   // barrier 2
            if (tid < 16)
                bhL[tid * 512 + t] = redL[tid] + redL[16 + tid] + redL[32 + tid] + redL[48 + tid] + b3v;
            __syncthreads();   // barrier 3
            p1a = p1an; p1b = p1bn;
        }
        // bulk write beta
        for (int i = tid; i < 8192; i += 256) beta_out[i] = bhL[i];
    }
}

// ============ K2b: dense C fill (zeros + latest-occurrence betas) ============
__global__ __launch_bounds__(256) void k2b_fill(
    const int* __restrict__ c_seq, const float* __restrict__ beta_in,
    float* __restrict__ C_out)
{
    __shared__ int   scs[Sq];
    __shared__ float sbt[Sq];
    const int bid = blockIdx.x, tid = threadIdx.x;
    const int b = bid / 40, rem = bid % 40;
    const int chunk = rem >> 2, q = rem & 3;

    for (int i = tid; i < Sq; i += 256) {
        scs[i] = c_seq[b * Sq + i];
        sbt[i] = beta_in[b * Sq + i];
    }
    __syncthreads();

    const int c0 = chunk * 1024 + tid * 4;
    if (c0 >= NCq) return;

    float cur0 = 0.f, cur1 = 0.f, cur2 = 0.f, cur3 = 0.f;
    const int tlo = q * 128, thi = tlo + 128;
    float* base = C_out + (size_t)b * Sq * NCq + c0;

    for (int t = 0; t < tlo; ++t) {
        int ct = scs[t] - c0; float bv = sbt[t];
        cur0 = (ct == 0) ? bv : cur0;
        cur1 = (ct == 1) ? bv : cur1;
        cur2 = (ct == 2) ? bv : cur2;
        cur3 = (ct == 3) ? bv : cur3;
    }
    for (int t = tlo; t < thi; ++t) {
        int ct = scs[t] - c0; float bv = sbt[t];
        cur0 = (ct == 0) ? bv : cur0;
        cur1 = (ct == 1) ? bv : cur1;
        cur2 = (ct == 2) ? bv : cur2;
        cur3 = (ct == 3) ? bv : cur3;
        *(float4*)(base + (size_t)t * NCq) = make_float4(cur0, cur1, cur2, cur3);
    }
}

// ============ K3: alpha = mlp1(h_seq) ============
__global__ __launch_bounds__(256) void k3_alpha(
    const float* __restrict__ hseq,
    const float* __restrict__ W1, const float* __restrict__ b1,
    const float* __restrict__ W2, const float* __restrict__ b2,
    const float* __restrict__ W3, const float* __restrict__ b3,
    float* __restrict__ alpha_out)
{
    __shared__ float Hs[32 * 128];
    __shared__ float T1[32 * 128];
    __shared__ float red[4][16];
    const int blk = blockIdx.x, tid = threadIdx.x;
    const int row0 = blk * 32;

    for (int e = tid; e < 1024; e += 256) {
        int r = e >> 5, q = e & 31;
        *(float4*)&Hs[r * 128 + 4 * q] =
            *(const float4*)&hseq[(size_t)(row0 + r) * 128 + 4 * q];
    }
    __syncthreads();

    const int j = tid & 127, rh = tid >> 7;
    const float b1j = b1[j], b2j = b2[j], w3j = W3[j];
    float acc[16];
#pragma unroll
    for (int r = 0; r < 16; ++r) acc[r] = b1j;
    for (int k = 0; k < 128; ++k) {
        float w = W1[k * 128 + j];
#pragma unroll
        for (int r = 0; r < 16; ++r)
            acc[r] = fmaf(Hs[(rh * 16 + r) * 128 + k], w, acc[r]);
    }
#pragma unroll
    for (int r = 0; r < 16; ++r) {
        acc[r] = fmaxf(acc[r], 0.f);
        T1[(rh * 16 + r) * 128 + j] = acc[r];
    }
    __syncthreads();
    float acc2[16];
#pragma unroll
    for (int r = 0; r < 16; ++r) acc2[r] = b2j;
    for (int k = 0; k < 128; ++k) {
        float w = W2[k * 128 + j];
#pragma unroll
        for (int r = 0; r < 16; ++r)
            acc2[r] = fmaf(T1[(rh * 16 + r) * 128 + k], w, acc2[r]);
    }
#pragma unroll
    for (int r = 0; r < 16; ++r) {
        float p = fmaxf(acc2[r], 0.f) * w3j;
#pragma unroll
        for (int off = 1; off < 64; off <<= 1) p += __shfl_xor(p, off);
        if ((tid & 63) == 0) red[tid >> 6][r] = p;
    }
    __syncthreads();
    if (tid < 32) {
        int rr = tid & 15, g = tid >> 4;
        alpha_out[row0 + g * 16 + rr] = red[2 * g][rr] + red[2 * g + 1][rr] + b3[0];
    }
}

extern "C" void kernel_launch(void* const* d_in, const int* in_sizes, int n_in,
                              void* d_out, int out_size, void* d_ws, size_t ws_size,
                              hipStream_t stream) {
    const int*   c_seq = (const int*)d_in[0];
    const int*   d_seq = (const int*)d_in[1];
    const float* r_seq = (const float*)d_in[2];
    const float* D1_w  = (const float*)d_in[3];
    const float* D2_w  = (const float*)d_in[4];
    const float* v_r   = (const float*)d_in[5];
    const float* v_b   = (const float*)d_in[6];
    const float* W_ih  = (const float*)d_in[7];
    const float* W_hh  = (const float*)d_in[8];
    const float* b_ih  = (const float*)d_in[9];
    const float* b_hh  = (const float*)d_in[10];
    const float* m1W1  = (const float*)d_in[11];
    const float* m1b1  = (const float*)d_in[12];
    const float* m1W2  = (const float*)d_in[13];
    const float* m1b2  = (const float*)d_in[14];
    const float* m1W3  = (const float*)d_in[15];
    const float* m1b3  = (const float*)d_in[16];
    const float* m2W1  = (const float*)d_in[17];
    const float* m2b1  = (const float*)d_in[18];
    const float* m2W2  = (const float*)d_in[19];
    const float* m2b2  = (const float*)d_in[20];
    const float* m2W3  = (const float*)d_in[21];
    const float* m2b3  = (const float*)d_in[22];

    float* out   = (float*)d_out;
    float* alpha = out;                 // [16*512]
    float* beta  = out + 8192;          // [16*512]
    float* gamma = out + 16384;         // [16*512]
    float* hseq  = out + 24576;         // [16*512*128]
    float* Cseq  = out + 1073152;       // [16*512*10000]
    float* ws    = (float*)d_ws;

    hipLaunchKernelGGL(k0_prep, dim3(161), dim3(256), 0, stream,
                       c_seq, d_seq, D1_w, W_ih, v_r, v_b, m2W1, ws, gamma);
    hipLaunchKernelGGL(k1_gemm, dim3(1024), dim3(256), 0, stream,
                       d_seq, D2_w, m2W1, b_ih, b_hh, r_seq, m2b1, ws);
    hipLaunchKernelGGL(k2_scan, dim3(2), dim3(256), 0, stream,
                       W_hh, b_hh, m2W2, m2b2, m2W3, m2b3, ws, hseq, beta);
    hipLaunchKernelGGL(k2b_fill, dim3(640), dim3(256), 0, stream,
                       c_seq, beta, Cseq);
    hipLaunchKernelGGL(k3_alpha, dim3(256), dim3(256), 0, stream,
                       hseq, m1W1, m1b1, m1W2, m1b2, m1W3, m1b3, alpha);
}

// Round 5
// 757.204 us; speedup vs baseline: 1.5424x; 1.5424x over previous
//
#include <hip/hip_runtime.h>

#define Bq   16
#define Sq   512
#define Vq   128
#define NCq  10000

typedef __attribute__((ext_vector_type(8))) short short8v;
typedef __attribute__((ext_vector_type(4))) float f32x4;

// ---- workspace layout (float offsets) ----
#define OFF_XP     0u          // [512 t][96 r4][16 b][4]  xp + biases + r*wvr folded
#define OFF_PRE1   3145728u    // [8192 m][128 j]          pre1 + b1 + r*wvr1 folded
#define OFF_WTIH   4194304u    // [128 k][384 g]           W_ih[:, :V] transposed
#define OFF_WVRIH  4243456u    // [384]  v_r @ W_ih[:, V:2V].T
#define OFF_WVR1   4243840u    // [128]  v_r @ m2_W1[2V:3V, :]
#define OFF_WVB    4243968u    // [128]  v_beta @ m2_W1[0:V, :]
#define OFF_PO     4244096u    // int [512 t][16 b] prev occurrence (-1 if none)

__device__ __forceinline__ unsigned short f2bf(float x) {
    unsigned u = __builtin_bit_cast(unsigned, x);
    unsigned r = (u + 0x7fffu + ((u >> 16) & 1u)) >> 16;
    return (unsigned short)r;
}

// ============ K0: transpose, small vectors, prev-occurrence, gamma ============
__global__ __launch_bounds__(256) void k0_prep(
    const int* __restrict__ c_seq, const int* __restrict__ d_seq,
    const float* __restrict__ D1_w,
    const float* __restrict__ W_ih,
    const float* __restrict__ v_r, const float* __restrict__ v_beta,
    const float* __restrict__ m2W1,
    float* __restrict__ ws, float* __restrict__ gamma_out)
{
    const int blk = blockIdx.x, tid = threadIdx.x;

    if (blk < 128) {
        float* WTIH = ws + OFF_WTIH;
        int base = blk * 384;
        for (int i = tid; i < 384; i += 256) {
            int e = base + i;
            int k = e / 384, g = e % 384;
            WTIH[e] = W_ih[g * 256 + k];
        }
    } else if (blk == 128) {
        float* WVRIH = ws + OFF_WVRIH;
        float* WVR1  = ws + OFF_WVR1;
        float* WVB   = ws + OFF_WVB;
        for (int g = tid; g < 384; g += 256) {
            float a = 0.f;
            for (int k = 0; k < 128; ++k) a = fmaf(v_r[k], W_ih[g * 256 + 128 + k], a);
            WVRIH[g] = a;
        }
        if (tid < 128) {
            float a = 0.f, b = 0.f;
            for (int k = 0; k < 128; ++k) {
                a = fmaf(v_r[k],    m2W1[(256 + k) * 128 + tid], a);
                b = fmaf(v_beta[k], m2W1[k * 128 + tid],         b);
            }
            WVR1[tid] = a; WVB[tid] = b;
        }
    } else if (blk < 145) {
        const int b = blk - 129;
        __shared__ int cs[Sq];
        for (int i = tid; i < Sq; i += 256) cs[i] = c_seq[b * Sq + i];
        __syncthreads();
        int* PO = (int*)(ws + OFF_PO);
        for (int t = tid; t < Sq; t += 256) {
            int c = cs[t];
            int po = -1;
            for (int u = t - 1; u >= 0; --u) if (cs[u] == c) { po = u; break; }
            PO[t * 16 + b] = po;
        }
    } else {
        const int b = blk - 145;
        for (int s = tid; s < Sq; s += 256)
            gamma_out[b * Sq + s] = D1_w[d_seq[b * Sq + s]];
    }
}

// ============ K1: batched GEMM [8192,128]x[128,512] -> xp4 | pre1 (biases folded) ============
__global__ __launch_bounds__(256) void k1_gemm(
    const int* __restrict__ d_seq, const float* __restrict__ D2_w,
    const float* __restrict__ m2W1,
    const float* __restrict__ b_ih, const float* __restrict__ b_hh,
    const float* __restrict__ r_seq, const float* __restrict__ m2b1,
    float* __restrict__ ws)
{
    __shared__ float As[64 * 128];   // [r][k]
    __shared__ float Bs[128 * 64];   // [k][c]
    const int blk = blockIdx.x, tid = threadIdx.x;
    const int nc = blk & 7;
    const int m0 = (blk >> 3) * 64;
    const float* WTIH = ws + OFF_WTIH;

    const float4* D2v = (const float4*)D2_w;
    for (int e = tid; e < 2048; e += 256) {
        int r = e >> 5, q = e & 31;
        int d = d_seq[m0 + r];
        *(float4*)&As[r * 128 + 4 * q] = D2v[d * 32 + q];
    }
    for (int e = tid; e < 2048; e += 256) {
        int k = e >> 4, q = e & 15;
        float4 v;
        if (nc < 6) v = *(const float4*)&WTIH[k * 384 + nc * 64 + 4 * q];
        else        v = *(const float4*)&m2W1[(128 + k) * 128 + (nc - 6) * 64 + 4 * q];
        *(float4*)&Bs[k * 64 + 4 * q] = v;
    }
    __syncthreads();

    const int tx = tid & 15, ty = tid >> 4;
    const int c0 = 4 * tx, r0 = 4 * ty;
    float acc[4][4];
#pragma unroll
    for (int i = 0; i < 4; ++i)
#pragma unroll
        for (int j = 0; j < 4; ++j) acc[i][j] = 0.f;

    for (int k = 0; k < 128; ++k) {
        float4 bv = *(const float4*)&Bs[k * 64 + c0];
#pragma unroll
        for (int i = 0; i < 4; ++i) {
            float a = As[(r0 + i) * 128 + k];
            acc[i][0] = fmaf(a, bv.x, acc[i][0]);
            acc[i][1] = fmaf(a, bv.y, acc[i][1]);
            acc[i][2] = fmaf(a, bv.z, acc[i][2]);
            acc[i][3] = fmaf(a, bv.w, acc[i][3]);
        }
    }

    float rsv[4];
#pragma unroll
    for (int i = 0; i < 4; ++i) rsv[i] = r_seq[m0 + r0 + i];

    if (nc < 6) {
        const int grow0 = nc * 64 + c0;
        float4 bi  = *(const float4*)&b_ih[grow0];
        float4 wv4 = *(const float4*)&(ws + OFF_WVRIH)[grow0];
        float4 bh4 = make_float4(0.f, 0.f, 0.f, 0.f);
        if (nc < 4) bh4 = *(const float4*)&b_hh[grow0];   // r,z gates get b_hh folded
        float* XP4 = ws + OFF_XP;
        const int r4 = grow0 >> 2;
#pragma unroll
        for (int i = 0; i < 4; ++i) {
            int row = m0 + r0 + i;
            int t = row & 511, bb = row >> 9;
            float4 v;
            v.x = acc[i][0] + bi.x + bh4.x + rsv[i] * wv4.x;
            v.y = acc[i][1] + bi.y + bh4.y + rsv[i] * wv4.y;
            v.z = acc[i][2] + bi.z + bh4.z + rsv[i] * wv4.z;
            v.w = acc[i][3] + bi.w + bh4.w + rsv[i] * wv4.w;
            *(float4*)&XP4[((t * 96 + r4) * 16 + bb) * 4] = v;
        }
    } else {
        const int j0 = (nc - 6) * 64 + c0;
        float4 b1v = *(const float4*)&m2b1[j0];
        float4 wr1 = *(const float4*)&(ws + OFF_WVR1)[j0];
        float* PRE1 = ws + OFF_PRE1;
#pragma unroll
        for (int i = 0; i < 4; ++i) {
            int row = m0 + r0 + i;
            float4 v;
            v.x = acc[i][0] + b1v.x + rsv[i] * wr1.x;
            v.y = acc[i][1] + b1v.y + rsv[i] * wr1.y;
            v.z = acc[i][2] + b1v.z + rsv[i] * wr1.z;
            v.w = acc[i][3] + b1v.w + rsv[i] * wr1.w;
            *(float4*)&PRE1[(size_t)row * 128 + j0] = v;
        }
    }
}

// ============ K2: MFMA scans, 512 threads (8 waves). blk0: GRU, blk1: beta ============
#define PLN 136          // bf16 plane stride in ushorts (batch row pitch, padded)
#define PLSZ (16*PLN+8)  // ushorts per plane

__global__ __launch_bounds__(512, 1) void k2_scan(
    const float* __restrict__ W_hh, const float* __restrict__ b_hh,
    const float* __restrict__ m2W2, const float* __restrict__ m2b2,
    const float* __restrict__ m2W3, const float* __restrict__ m2b3,
    float* __restrict__ ws,
    float* __restrict__ hseq_out, float* __restrict__ beta_out)
{
    __shared__ __align__(16) unsigned char smem[70416];
    const int tid = threadIdx.x;
    const int l = tid & 63, wv = tid >> 6;   // 8 waves
    const int qq = l >> 4, cb = l & 15;

    if (blockIdx.x == 0) {
        // ---------------- GRU, all 16 batches, one block ----------------
        // wave w owns output rows j = 16w..16w+15 for all 3 gates.
        unsigned short* hP = (unsigned short*)smem;          // [2][PLSZ]
        short8v aH[3][4];
#pragma unroll
        for (int g = 0; g < 3; ++g) {
            const float* wrow = W_hh + (g * 128 + 16 * wv + cb) * 128;
#pragma unroll
            for (int kf = 0; kf < 4; ++kf) {
                short8v hi;
#pragma unroll
                for (int e = 0; e < 8; ++e) hi[e] = (short)f2bf(wrow[kf * 32 + qq * 8 + e]);
                aH[g][kf] = hi;
            }
        }
        float bhn[4];
        *(float4*)bhn = *(const float4*)&b_hh[256 + 16 * wv + 4 * qq];
        const float* XP4 = ws + OFF_XP;

        f32x4 pxA[3], pxB[3], pxC[3];
#pragma unroll
        for (int g = 0; g < 3; ++g) {
            const int r4 = 32 * g + 4 * wv + qq;
            pxA[g] = *(const f32x4*)&XP4[((0 * 96 + r4) * 16 + cb) * 4];
            pxB[g] = *(const f32x4*)&XP4[((1 * 96 + r4) * 16 + cb) * 4];
            pxC[g] = (f32x4){0.f, 0.f, 0.f, 0.f};
        }
        float hold[4] = {0.f, 0.f, 0.f, 0.f};
        for (int i = tid; i < 2 * PLSZ; i += 512) hP[i] = 0;
        __syncthreads();

        for (int t = 0; t < 512; ++t) {
            const unsigned short* HI = hP + (t & 1) * PLSZ;
            unsigned short* HIn = hP + ((t + 1) & 1) * PLSZ;
            if (t < 510) {
#pragma unroll
                for (int g = 0; g < 3; ++g) {
                    const int r4 = 32 * g + 4 * wv + qq;
                    pxC[g] = *(const f32x4*)&XP4[(((t + 2) * 96 + r4) * 16 + cb) * 4];
                }
            }
            f32x4 C0 = {0.f,0.f,0.f,0.f}, C1 = {0.f,0.f,0.f,0.f}, C2 = {0.f,0.f,0.f,0.f};
#pragma unroll
            for (int kf = 0; kf < 4; ++kf) {
                short8v Bh = *(const short8v*)(HI + cb * PLN + kf * 32 + qq * 8);
                C0 = __builtin_amdgcn_mfma_f32_16x16x32_bf16(aH[0][kf], Bh, C0, 0, 0, 0);
                C1 = __builtin_amdgcn_mfma_f32_16x16x32_bf16(aH[1][kf], Bh, C1, 0, 0, 0);
                C2 = __builtin_amdgcn_mfma_f32_16x16x32_bf16(aH[2][kf], Bh, C2, 0, 0, 0);
            }
            float hnew[4];
#pragma unroll
            for (int i = 0; i < 4; ++i) {
                float pr = C0[i] + pxA[0][i];
                float pz = C1[i] + pxA[1][i];
                float r = 1.f / (1.f + __expf(-pr));
                float z = 1.f / (1.f + __expf(-pz));
                float hn = C2[i] + bhn[i];
                float npre = fmaf(r, hn, pxA[2][i]);
                float ax = fabsf(npre);
                float e2 = __expf(-2.f * ax);
                float n = copysignf((1.f - e2) / (1.f + e2), npre);
                float hv = (1.f - z) * n + z * hold[i];
                hold[i] = hv;
                hnew[i] = hv;
            }
            *(float4*)&hseq_out[(size_t)(cb * 512 + t) * 128 + 16 * wv + 4 * qq] =
                make_float4(hnew[0], hnew[1], hnew[2], hnew[3]);
            {
                unsigned short h0 = f2bf(hnew[0]), h1 = f2bf(hnew[1]);
                unsigned short h2 = f2bf(hnew[2]), h3 = f2bf(hnew[3]);
                uint2 hw;
                hw.x = (unsigned)h0 | ((unsigned)h1 << 16);
                hw.y = (unsigned)h2 | ((unsigned)h3 << 16);
                *(uint2*)(HIn + cb * PLN + 16 * wv + 4 * qq) = hw;
            }
#pragma unroll
            for (int g = 0; g < 3; ++g) { pxA[g] = pxB[g]; pxB[g] = pxC[g]; }
            __syncthreads();
        }
    } else {
        // ---------------- beta scan, all 16 batches, one block ----------------
        float* bhL = (float*)smem;                               // [16][512]
        int* poT = (int*)(smem + 32768);                         // [512][16]
        unsigned short* h1P = (unsigned short*)(smem + 65536);   // [PLSZ]
        float* redL = (float*)(smem + 69904);                    // [8][16]

        {
            const int* POg = (const int*)(ws + OFF_PO);
            for (int i = tid; i < 8192; i += 512) poT[i] = POg[i];
        }
        short8v aH[4];
#pragma unroll
        for (int kf = 0; kf < 4; ++kf) {
            short8v hi;
#pragma unroll
            for (int e = 0; e < 8; ++e)
                hi[e] = (short)f2bf(m2W2[(kf * 32 + qq * 8 + e) * 128 + 16 * wv + cb]);
            aH[kf] = hi;
        }
        float w3C[4], b2C[4];
        *(float4*)w3C = *(const float4*)&m2W3[16 * wv + 4 * qq];
        *(float4*)b2C = *(const float4*)&m2b2[16 * wv + 4 * qq];
        const float b3v = m2b3[0];

        const int bb2 = tid & 15, j4 = tid >> 4;   // j4 in [0,32), 4 j's each
        float wvb[4];
        *(float4*)wvb = *(const float4*)&(ws + OFF_WVB)[j4 * 4];
        const float* p1base = ws + OFF_PRE1 + (size_t)(bb2 * 512) * 128 + j4 * 4;
        f32x4 p1a = *(const f32x4*)&p1base[0];
        f32x4 p1b = *(const f32x4*)&p1base[128];
        f32x4 p1c = {0.f, 0.f, 0.f, 0.f};
        float btap = 0.f;    // beta[t-1] for batch bb2
        __syncthreads();

        for (int t = 0; t < 512; ++t) {
            // phase A: h1 + bhL[t-1] publish
            if (t < 510) p1c = *(const f32x4*)&p1base[(size_t)(t + 2) * 128];
            int po = poT[t * 16 + bb2];
            float bp = (po == t - 1) ? btap : ((po >= 0) ? bhL[bb2 * 512 + po] : 0.f);
            if (t > 0 && j4 == 0) bhL[bb2 * 512 + (t - 1)] = btap;
            {
                unsigned short h0 = f2bf(fmaxf(0.f, fmaf(bp, wvb[0], p1a[0])));
                unsigned short h1 = f2bf(fmaxf(0.f, fmaf(bp, wvb[1], p1a[1])));
                unsigned short h2 = f2bf(fmaxf(0.f, fmaf(bp, wvb[2], p1a[2])));
                unsigned short h3 = f2bf(fmaxf(0.f, fmaf(bp, wvb[3], p1a[3])));
                uint2 hw;
                hw.x = (unsigned)h0 | ((unsigned)h1 << 16);
                hw.y = (unsigned)h2 | ((unsigned)h3 << 16);
                *(uint2*)(h1P + bb2 * PLN + j4 * 4) = hw;
            }
            __syncthreads();   // barrier 1: planes ready
            // phase B: MFMA + w3 dot
            f32x4 C = {0.f, 0.f, 0.f, 0.f};
#pragma unroll
            for (int kf = 0; kf < 4; ++kf) {
                short8v Bh = *(const short8v*)(h1P + cb * PLN + kf * 32 + qq * 8);
                C = __builtin_amdgcn_mfma_f32_16x16x32_bf16(aH[kf], Bh, C, 0, 0, 0);
            }
            float part = 0.f;
#pragma unroll
            for (int i = 0; i < 4; ++i)
                part = fmaf(fmaxf(0.f, C[i] + b2C[i]), w3C[i], part);
            part += __shfl_xor(part, 16);
            part += __shfl_xor(part, 32);
            if (qq == 0) redL[wv * 16 + cb] = part;
            __syncthreads();   // barrier 2: redL ready (also fences plane reads)
            float bta = b3v;
#pragma unroll
            for (int w = 0; w < 8; ++w) bta += redL[w * 16 + bb2];
            btap = bta;
            p1a = p1b; p1b = p1c;
        }
        if (j4 == 0) bhL[bb2 * 512 + 511] = btap;
        __syncthreads();
        for (int i = tid; i < 8192; i += 512) beta_out[i] = bhL[i];
    }
}

// ============ K2b: dense C fill (zeros + latest-occurrence betas) ============
__global__ __launch_bounds__(256) void k2b_fill(
    const int* __restrict__ c_seq, const float* __restrict__ beta_in,
    float* __restrict__ C_out)
{
    __shared__ int   scs[Sq];
    __shared__ float sbt[Sq];
    const int bid = blockIdx.x, tid = threadIdx.x;
    const int b = bid / 40, rem = bid % 40;
    const int chunk = rem >> 2, q = rem & 3;

    for (int i = tid; i < Sq; i += 256) {
        scs[i] = c_seq[b * Sq + i];
        sbt[i] = beta_in[b * Sq + i];
    }
    __syncthreads();

    const int c0 = chunk * 1024 + tid * 4;
    if (c0 >= NCq) return;

    float cur0 = 0.f, cur1 = 0.f, cur2 = 0.f, cur3 = 0.f;
    const int tlo = q * 128, thi = tlo + 128;
    float* base = C_out + (size_t)b * Sq * NCq + c0;

    for (int t = 0; t < tlo; ++t) {
        int ct = scs[t] - c0; float bv = sbt[t];
        cur0 = (ct == 0) ? bv : cur0;
        cur1 = (ct == 1) ? bv : cur1;
        cur2 = (ct == 2) ? bv : cur2;
        cur3 = (ct == 3) ? bv : cur3;
    }
    for (int t = tlo; t < thi; ++t) {
        int ct = scs[t] - c0; float bv = sbt[t];
        cur0 = (ct == 0) ? bv : cur0;
        cur1 = (ct == 1) ? bv : cur1;
        cur2 = (ct == 2) ? bv : cur2;
        cur3 = (ct == 3) ? bv : cur3;
        *(float4*)(base + (size_t)t * NCq) = make_float4(cur0, cur1, cur2, cur3);
    }
}

// ============ K3: alpha = mlp1(h_seq) ============
__global__ __launch_bounds__(256) void k3_alpha(
    const float* __restrict__ hseq,
    const float* __restrict__ W1, const float* __restrict__ b1,
    const float* __restrict__ W2, const float* __restrict__ b2,
    const float* __restrict__ W3, const float* __restrict__ b3,
    float* __restrict__ alpha_out)
{
    __shared__ float Hs[32 * 128];
    __shared__ float T1[32 * 128];
    __shared__ float red[4][16];
    const int blk = blockIdx.x, tid = threadIdx.x;
    const int row0 = blk * 32;

    for (int e = tid; e < 1024; e += 256) {
        int r = e >> 5, q = e & 31;
        *(float4*)&Hs[r * 128 + 4 * q] =
            *(const float4*)&hseq[(size_t)(row0 + r) * 128 + 4 * q];
    }
    __syncthreads();

    const int j = tid & 127, rh = tid >> 7;
    const float b1j = b1[j], b2j = b2[j], w3j = W3[j];
    float acc[16];
#pragma unroll
    for (int r = 0; r < 16; ++r) acc[r] = b1j;
    for (int k = 0; k < 128; ++k) {
        float w = W1[k * 128 + j];
#pragma unroll
        for (int r = 0; r < 16; ++r)
            acc[r] = fmaf(Hs[(rh * 16 + r) * 128 + k], w, acc[r]);
    }
#pragma unroll
    for (int r = 0; r < 16; ++r) {
        acc[r] = fmaxf(acc[r], 0.f);
        T1[(rh * 16 + r) * 128 + j] = acc[r];
    }
    __syncthreads();
    float acc2[16];
#pragma unroll
    for (int r = 0; r < 16; ++r) acc2[r] = b2j;
    for (int k = 0; k < 128; ++k) {
        float w = W2[k * 128 + j];
#pragma unroll
        for (int r = 0; r < 16; ++r)
            acc2[r] = fmaf(T1[(rh * 16 + r) * 128 + k], w, acc2[r]);
    }
#pragma unroll
    for (int r = 0; r < 16; ++r) {
        float p = fmaxf(acc2[r], 0.f) * w3j;
#pragma unroll
        for (int off = 1; off < 64; off <<= 1) p += __shfl_xor(p, off);
        if ((tid & 63) == 0) red[tid >> 6][r] = p;
    }
    __syncthreads();
    if (tid < 32) {
        int rr = tid & 15, g = tid >> 4;
        alpha_out[row0 + g * 16 + rr] = red[2 * g][rr] + red[2 * g + 1][rr] + b3[0];
    }
}

extern "C" void kernel_launch(void* const* d_in, const int* in_sizes, int n_in,
                              void* d_out, int out_size, void* d_ws, size_t ws_size,
                              hipStream_t stream) {
    const int*   c_seq = (const int*)d_in[0];
    const int*   d_seq = (const int*)d_in[1];
    const float* r_seq = (const float*)d_in[2];
    const float* D1_w  = (const float*)d_in[3];
    const float* D2_w  = (const float*)d_in[4];
    const float* v_r   = (const float*)d_in[5];
    const float* v_b   = (const float*)d_in[6];
    const float* W_ih  = (const float*)d_in[7];
    const float* W_hh  = (const float*)d_in[8];
    const float* b_ih  = (const float*)d_in[9];
    const float* b_hh  = (const float*)d_in[10];
    const float* m1W1  = (const float*)d_in[11];
    const float* m1b1  = (const float*)d_in[12];
    const float* m1W2  = (const float*)d_in[13];
    const float* m1b2  = (const float*)d_in[14];
    const float* m1W3  = (const float*)d_in[15];
    const float* m1b3  = (const float*)d_in[16];
    const float* m2W1  = (const float*)d_in[17];
    const float* m2b1  = (const float*)d_in[18];
    const float* m2W2  = (const float*)d_in[19];
    const float* m2b2  = (const float*)d_in[20];
    const float* m2W3  = (const float*)d_in[21];
    const float* m2b3  = (const float*)d_in[22];

    float* out   = (float*)d_out;
    float* alpha = out;                 // [16*512]
    float* beta  = out + 8192;          // [16*512]
    float* gamma = out + 16384;         // [16*512]
    float* hseq  = out + 24576;         // [16*512*128]
    float* Cseq  = out + 1073152;       // [16*512*10000]
    float* ws    = (float*)d_ws;

    hipLaunchKernelGGL(k0_prep, dim3(161), dim3(256), 0, stream,
                       c_seq, d_seq, D1_w, W_ih, v_r, v_b, m2W1, ws, gamma);
    hipLaunchKernelGGL(k1_gemm, dim3(1024), dim3(256), 0, stream,
                       d_seq, D2_w, m2W1, b_ih, b_hh, r_seq, m2b1, ws);
    hipLaunchKernelGGL(k2_scan, dim3(2), dim3(512), 0, stream,
                       W_hh, b_hh, m2W2, m2b2, m2W3, m2b3, ws, hseq, beta);
    hipLaunchKernelGGL(k2b_fill, dim3(640), dim3(256), 0, stream,
                       c_seq, beta, Cseq);
    hipLaunchKernelGGL(k3_alpha, dim3(256), dim3(256), 0, stream,
                       hseq, m1W1, m1b1, m1W2, m1b2, m1W3, m1b3, alpha);
}

// Round 6
// 750.693 us; speedup vs baseline: 1.5558x; 1.0087x over previous
//
#include <hip/hip_runtime.h>

#define Bq   16
#define Sq   512
#define Vq   128
#define NCq  10000

typedef __attribute__((ext_vector_type(8))) short short8v;
typedef __attribute__((ext_vector_type(4))) float f32x4;

// ---- workspace layout ----
// ushort region (from ws base):
//   XPB:  [4 bg][512 t][96 r4][4 b][4 e] bf16, 3,145,728 ushorts
//   P1B:  [512 t][16 b][128 j] bf16,        1,048,576 ushorts
// float region (float offsets from ws base):
#define OFF_P1B_U  3145728u
#define OFF_WTIH   2097152u    // [128 k][384 g] W_ih[:, :V]^T
#define OFF_WVRIH  2146304u    // [384]
#define OFF_WVR1   2146688u    // [128]
#define OFF_WVB    2146816u    // [128]
#define OFF_PO     2146944u    // int [512 t][16 b]

#define PLN 136
#define PLSZ (16*PLN+8)

__device__ __forceinline__ unsigned short f2bf(float x) {
    unsigned u = __builtin_bit_cast(unsigned, x);
    unsigned r = (u + 0x7fffu + ((u >> 16) & 1u)) >> 16;
    return (unsigned short)r;
}
__device__ __forceinline__ float bfhi(unsigned u) {        // low ushort -> float
    return __builtin_bit_cast(float, u << 16);
}
__device__ __forceinline__ float bflo(unsigned u) {        // high ushort -> float
    return __builtin_bit_cast(float, u & 0xffff0000u);
}
__device__ __forceinline__ void gload_lds16(const void* g, void* l) {
    __builtin_amdgcn_global_load_lds(
        (const __attribute__((address_space(1))) unsigned int*)g,
        (__attribute__((address_space(3))) unsigned int*)l, 16, 0, 0);
}

// ============ K0: transpose, small vectors, prev-occurrence, gamma ============
__global__ __launch_bounds__(256) void k0_prep(
    const int* __restrict__ c_seq, const int* __restrict__ d_seq,
    const float* __restrict__ D1_w,
    const float* __restrict__ W_ih,
    const float* __restrict__ v_r, const float* __restrict__ v_beta,
    const float* __restrict__ m2W1,
    float* __restrict__ ws, float* __restrict__ gamma_out)
{
    const int blk = blockIdx.x, tid = threadIdx.x;

    if (blk < 128) {
        float* WTIH = ws + OFF_WTIH;
        int base = blk * 384;
        for (int i = tid; i < 384; i += 256) {
            int e = base + i;
            int k = e / 384, g = e % 384;
            WTIH[e] = W_ih[g * 256 + k];
        }
    } else if (blk == 128) {
        float* WVRIH = ws + OFF_WVRIH;
        float* WVR1  = ws + OFF_WVR1;
        float* WVB   = ws + OFF_WVB;
        for (int g = tid; g < 384; g += 256) {
            float a = 0.f;
            for (int k = 0; k < 128; ++k) a = fmaf(v_r[k], W_ih[g * 256 + 128 + k], a);
            WVRIH[g] = a;
        }
        if (tid < 128) {
            float a = 0.f, b = 0.f;
            for (int k = 0; k < 128; ++k) {
                a = fmaf(v_r[k],    m2W1[(256 + k) * 128 + tid], a);
                b = fmaf(v_beta[k], m2W1[k * 128 + tid],         b);
            }
            WVR1[tid] = a; WVB[tid] = b;
        }
    } else if (blk < 145) {
        const int b = blk - 129;
        __shared__ int cs[Sq];
        for (int i = tid; i < Sq; i += 256) cs[i] = c_seq[b * Sq + i];
        __syncthreads();
        int* PO = (int*)(ws + OFF_PO);
        for (int t = tid; t < Sq; t += 256) {
            int c = cs[t];
            int po = -1;
            for (int u = t - 1; u >= 0; --u) if (cs[u] == c) { po = u; break; }
            PO[t * 16 + b] = po;
        }
    } else {
        const int b = blk - 145;
        for (int s = tid; s < Sq; s += 256)
            gamma_out[b * Sq + s] = D1_w[d_seq[b * Sq + s]];
    }
}

// ============ K1: batched GEMM -> xpb (bf16) | p1b (bf16), biases folded ============
__global__ __launch_bounds__(256) void k1_gemm(
    const int* __restrict__ d_seq, const float* __restrict__ D2_w,
    const float* __restrict__ m2W1,
    const float* __restrict__ b_ih, const float* __restrict__ b_hh,
    const float* __restrict__ r_seq, const float* __restrict__ m2b1,
    float* __restrict__ ws)
{
    __shared__ float As[64 * 128];
    __shared__ float Bs[128 * 64];
    const int blk = blockIdx.x, tid = threadIdx.x;
    const int nc = blk & 7;
    const int m0 = (blk >> 3) * 64;
    const float* WTIH = ws + OFF_WTIH;

    const float4* D2v = (const float4*)D2_w;
    for (int e = tid; e < 2048; e += 256) {
        int r = e >> 5, q = e & 31;
        int d = d_seq[m0 + r];
        *(float4*)&As[r * 128 + 4 * q] = D2v[d * 32 + q];
    }
    for (int e = tid; e < 2048; e += 256) {
        int k = e >> 4, q = e & 15;
        float4 v;
        if (nc < 6) v = *(const float4*)&WTIH[k * 384 + nc * 64 + 4 * q];
        else        v = *(const float4*)&m2W1[(128 + k) * 128 + (nc - 6) * 64 + 4 * q];
        *(float4*)&Bs[k * 64 + 4 * q] = v;
    }
    __syncthreads();

    const int tx = tid & 15, ty = tid >> 4;
    const int c0 = 4 * tx, r0 = 4 * ty;
    float acc[4][4];
#pragma unroll
    for (int i = 0; i < 4; ++i)
#pragma unroll
        for (int j = 0; j < 4; ++j) acc[i][j] = 0.f;

    for (int k = 0; k < 128; ++k) {
        float4 bv = *(const float4*)&Bs[k * 64 + c0];
#pragma unroll
        for (int i = 0; i < 4; ++i) {
            float a = As[(r0 + i) * 128 + k];
            acc[i][0] = fmaf(a, bv.x, acc[i][0]);
            acc[i][1] = fmaf(a, bv.y, acc[i][1]);
            acc[i][2] = fmaf(a, bv.z, acc[i][2]);
            acc[i][3] = fmaf(a, bv.w, acc[i][3]);
        }
    }

    float rsv[4];
#pragma unroll
    for (int i = 0; i < 4; ++i) rsv[i] = r_seq[m0 + r0 + i];

    if (nc < 6) {
        const int grow0 = nc * 64 + c0;
        float4 bi  = *(const float4*)&b_ih[grow0];
        float4 wv4 = *(const float4*)&(ws + OFF_WVRIH)[grow0];
        float4 bh4 = make_float4(0.f, 0.f, 0.f, 0.f);
        if (nc < 4) bh4 = *(const float4*)&b_hh[grow0];
        unsigned short* XPB = (unsigned short*)ws;
        const int r4 = grow0 >> 2;
#pragma unroll
        for (int i = 0; i < 4; ++i) {
            int row = m0 + r0 + i;
            int t = row & 511, bb = row >> 9;
            float vx = acc[i][0] + bi.x + bh4.x + rsv[i] * wv4.x;
            float vy = acc[i][1] + bi.y + bh4.y + rsv[i] * wv4.y;
            float vz = acc[i][2] + bi.z + bh4.z + rsv[i] * wv4.z;
            float vw = acc[i][3] + bi.w + bh4.w + rsv[i] * wv4.w;
            uint2 p;
            p.x = (unsigned)f2bf(vx) | ((unsigned)f2bf(vy) << 16);
            p.y = (unsigned)f2bf(vz) | ((unsigned)f2bf(vw) << 16);
            *(uint2*)&XPB[((size_t)((bb >> 2) * 512 + t)) * 1536 + r4 * 16 + (bb & 3) * 4] = p;
        }
    } else {
        const int j0 = (nc - 6) * 64 + c0;
        float4 b1v = *(const float4*)&m2b1[j0];
        float4 wr1 = *(const float4*)&(ws + OFF_WVR1)[j0];
        unsigned short* P1B = (unsigned short*)ws + OFF_P1B_U;
#pragma unroll
        for (int i = 0; i < 4; ++i) {
            int row = m0 + r0 + i;
            int t = row & 511, bb = row >> 9;
            float vx = acc[i][0] + b1v.x + rsv[i] * wr1.x;
            float vy = acc[i][1] + b1v.y + rsv[i] * wr1.y;
            float vz = acc[i][2] + b1v.z + rsv[i] * wr1.z;
            float vw = acc[i][3] + b1v.w + rsv[i] * wr1.w;
            uint2 p;
            p.x = (unsigned)f2bf(vx) | ((unsigned)f2bf(vy) << 16);
            p.y = (unsigned)f2bf(vz) | ((unsigned)f2bf(vw) << 16);
            *(uint2*)&P1B[((size_t)(t * 16 + bb)) * 128 + j0] = p;
        }
    }
}

// ============ K2: 8 blocks. blk 0..3: GRU (4 batches each). blk 4..7: beta (4 each) ============
__global__ __launch_bounds__(512, 1) void k2_scan(
    const float* __restrict__ W_hh, const float* __restrict__ b_hh,
    const float* __restrict__ m2W2, const float* __restrict__ m2b2,
    const float* __restrict__ m2W3, const float* __restrict__ m2b3,
    float* __restrict__ ws,
    float* __restrict__ hseq_out, float* __restrict__ beta_out)
{
    __shared__ __align__(16) unsigned char smem[23040];
    const int tid = threadIdx.x;
    const int l = tid & 63, wv = tid >> 6;
    const int qq = l >> 4, cb = l & 15;
    const int bgid = blockIdx.x;

    if (bgid < 4) {
        // ---------------- GRU, batches 4*bgid .. 4*bgid+3 ----------------
        unsigned short* hP  = (unsigned short*)smem;                  // [2][PLSZ]
        unsigned short* xps = (unsigned short*)(smem + 4 * PLSZ);     // [2][1536]
        const unsigned short* XPB = (const unsigned short*)ws;

        short8v aH[3][4];
#pragma unroll
        for (int g = 0; g < 3; ++g) {
            const float* wrow = W_hh + (g * 128 + 16 * wv + cb) * 128;
#pragma unroll
            for (int kf = 0; kf < 4; ++kf) {
                short8v hi;
#pragma unroll
                for (int e = 0; e < 8; ++e) hi[e] = (short)f2bf(wrow[kf * 32 + qq * 8 + e]);
                aH[g][kf] = hi;
            }
        }
        float bhn[4];
        *(float4*)bhn = *(const float4*)&b_hh[256 + 16 * wv + 4 * qq];
        float hold[4] = {0.f, 0.f, 0.f, 0.f};

        for (int i = tid; i < 2 * PLSZ; i += 512) hP[i] = 0;
        if (wv < 3) {
            const unsigned short* src = XPB + ((size_t)(bgid * 512)) * 1536 + wv * 512 + l * 8;
            gload_lds16(src, xps + wv * 512);
        }
        __syncthreads();

        for (int t = 0; t < 512; ++t) {
            // stage t+1 (drained by end-of-step barrier)
            if (t < 511 && wv < 3) {
                const unsigned short* src =
                    XPB + ((size_t)(bgid * 512 + t + 1)) * 1536 + wv * 512 + l * 8;
                gload_lds16(src, xps + ((t + 1) & 1) * 1536 + wv * 512);
            }
            const unsigned short* xcur = xps + (t & 1) * 1536;
            f32x4 px[3];
#pragma unroll
            for (int g = 0; g < 3; ++g) {
                uint2 u = *(const uint2*)(xcur + (32 * g + 4 * wv + qq) * 16 + (cb & 3) * 4);
                px[g][0] = bfhi(u.x); px[g][1] = bflo(u.x);
                px[g][2] = bfhi(u.y); px[g][3] = bflo(u.y);
            }
            const unsigned short* HI = hP + (t & 1) * PLSZ;
            unsigned short* HIn = hP + ((t + 1) & 1) * PLSZ;

            f32x4 C0 = {0.f,0.f,0.f,0.f}, C1 = {0.f,0.f,0.f,0.f}, C2 = {0.f,0.f,0.f,0.f};
#pragma unroll
            for (int kf = 0; kf < 4; ++kf) {
                short8v Bh = *(const short8v*)(HI + cb * PLN + kf * 32 + qq * 8);
                C0 = __builtin_amdgcn_mfma_f32_16x16x32_bf16(aH[0][kf], Bh, C0, 0, 0, 0);
                C1 = __builtin_amdgcn_mfma_f32_16x16x32_bf16(aH[1][kf], Bh, C1, 0, 0, 0);
                C2 = __builtin_amdgcn_mfma_f32_16x16x32_bf16(aH[2][kf], Bh, C2, 0, 0, 0);
            }
            float hnew[4];
#pragma unroll
            for (int i = 0; i < 4; ++i) {
                float pr = C0[i] + px[0][i];
                float pz = C1[i] + px[1][i];
                float r = 1.f / (1.f + __expf(-pr));
                float z = 1.f / (1.f + __expf(-pz));
                float hn = C2[i] + bhn[i];
                float npre = fmaf(r, hn, px[2][i]);
                float ax = fabsf(npre);
                float e2 = __expf(-2.f * ax);
                float n = copysignf((1.f - e2) / (1.f + e2), npre);
                float hv = (1.f - z) * n + z * hold[i];
                hold[i] = hv;
                hnew[i] = hv;
            }
            if (cb < 4) {
                *(float4*)&hseq_out[((size_t)((bgid * 4 + cb) * 512 + t)) * 128 + 16 * wv + 4 * qq] =
                    make_float4(hnew[0], hnew[1], hnew[2], hnew[3]);
                unsigned short h0 = f2bf(hnew[0]), h1 = f2bf(hnew[1]);
                unsigned short h2 = f2bf(hnew[2]), h3 = f2bf(hnew[3]);
                uint2 hw;
                hw.x = (unsigned)h0 | ((unsigned)h1 << 16);
                hw.y = (unsigned)h2 | ((unsigned)h3 << 16);
                *(uint2*)(HIn + cb * PLN + 16 * wv + 4 * qq) = hw;
            }
            __syncthreads();
        }
    } else {
        // ---------------- beta scan, batches 4*bq .. 4*bq+3 ----------------
        const int bq = bgid - 4;
        float* bhL = (float*)smem;                                  // [4][512]
        int*   poT = (int*)(smem + 8192);                           // [512][4]
        unsigned short* h1P  = (unsigned short*)(smem + 16384);     // [PLSZ]
        unsigned short* xpre = (unsigned short*)(smem + 20752);     // [2][512]
        float* redL = (float*)(smem + 22800);                       // [8][4]
        const unsigned short* P1B = (const unsigned short*)ws + OFF_P1B_U;

        {
            const int* POg = (const int*)(ws + OFF_PO);
            for (int i = tid; i < 2048; i += 512)
                poT[i] = POg[(i >> 2) * 16 + 4 * bq + (i & 3)];
        }
        for (int i = tid; i < PLSZ; i += 512) h1P[i] = 0;
        if (wv == 0)
            gload_lds16(P1B + ((size_t)(4 * bq)) * 128 + l * 8, xpre);

        short8v aH[4];
#pragma unroll
        for (int kf = 0; kf < 4; ++kf) {
            short8v hi;
#pragma unroll
            for (int e = 0; e < 8; ++e)
                hi[e] = (short)f2bf(m2W2[(kf * 32 + qq * 8 + e) * 128 + 16 * wv + cb]);
            aH[kf] = hi;
        }
        float w3C[4], b2C[4];
        *(float4*)w3C = *(const float4*)&m2W3[16 * wv + 4 * qq];
        *(float4*)b2C = *(const float4*)&m2b2[16 * wv + 4 * qq];
        const float b3v = m2b3[0];

        const int bb2 = tid & 3, j4 = (tid >> 2) & 31;
        const bool pa = tid < 128;
        float wvb[4] = {0.f, 0.f, 0.f, 0.f};
        if (pa) *(float4*)wvb = *(const float4*)&(ws + OFF_WVB)[j4 * 4];
        float btap = 0.f;
        __syncthreads();

        for (int t = 0; t < 512; ++t) {
            // phase A: h1 for step t
            if (pa) {
                int po = poT[t * 4 + bb2];
                float bp = (po == t - 1) ? btap : ((po >= 0) ? bhL[bb2 * 512 + po] : 0.f);
                uint2 u = *(const uint2*)(xpre + (t & 1) * 512 + bb2 * 128 + j4 * 4);
                float h0 = fmaxf(0.f, fmaf(bp, wvb[0], bfhi(u.x)));
                float h1 = fmaxf(0.f, fmaf(bp, wvb[1], bflo(u.x)));
                float h2 = fmaxf(0.f, fmaf(bp, wvb[2], bfhi(u.y)));
                float h3 = fmaxf(0.f, fmaf(bp, wvb[3], bflo(u.y)));
                uint2 hw;
                hw.x = (unsigned)f2bf(h0) | ((unsigned)f2bf(h1) << 16);
                hw.y = (unsigned)f2bf(h2) | ((unsigned)f2bf(h3) << 16);
                *(uint2*)(h1P + bb2 * PLN + j4 * 4) = hw;
            }
            if (tid < 4 && t > 0) bhL[tid * 512 + (t - 1)] = btap;
            __syncthreads();   // barrier 1: planes ready

            // stage t+1's pre1 during MFMA phase (drained at barrier 2)
            if (t < 511 && wv == 0)
                gload_lds16(P1B + ((size_t)((t + 1) * 16 + 4 * bq)) * 128 + l * 8,
                            xpre + ((t + 1) & 1) * 512);

            f32x4 C = {0.f, 0.f, 0.f, 0.f};
#pragma unroll
            for (int kf = 0; kf < 4; ++kf) {
                short8v Bh = *(const short8v*)(h1P + cb * PLN + kf * 32 + qq * 8);
                C = __builtin_amdgcn_mfma_f32_16x16x32_bf16(aH[kf], Bh, C, 0, 0, 0);
            }
            float part = 0.f;
#pragma unroll
            for (int i = 0; i < 4; ++i)
                part = fmaf(fmaxf(0.f, C[i] + b2C[i]), w3C[i], part);
            part += __shfl_xor(part, 16);
            part += __shfl_xor(part, 32);
            if (qq == 0 && cb < 4) redL[wv * 4 + cb] = part;
            __syncthreads();   // barrier 2: redL ready

            float bta = b3v;
#pragma unroll
            for (int w = 0; w < 8; ++w) bta += redL[w * 4 + (tid & 3)];
            btap = bta;
        }
        if (tid < 4) bhL[tid * 512 + 511] = btap;
        __syncthreads();
        for (int i = tid; i < 2048; i += 512)
            beta_out[(4 * bq + (i >> 9)) * 512 + (i & 511)] = bhL[i];
    }
}

// ============ K2b: dense C fill (zeros + latest-occurrence betas) ============
__global__ __launch_bounds__(256) void k2b_fill(
    const int* __restrict__ c_seq, const float* __restrict__ beta_in,
    float* __restrict__ C_out)
{
    __shared__ int   scs[Sq];
    __shared__ float sbt[Sq];
    const int bid = blockIdx.x, tid = threadIdx.x;
    const int b = bid / 40, rem = bid % 40;
    const int chunk = rem >> 2, q = rem & 3;

    for (int i = tid; i < Sq; i += 256) {
        scs[i] = c_seq[b * Sq + i];
        sbt[i] = beta_in[b * Sq + i];
    }
    __syncthreads();

    const int c0 = chunk * 1024 + tid * 4;
    if (c0 >= NCq) return;

    float cur0 = 0.f, cur1 = 0.f, cur2 = 0.f, cur3 = 0.f;
    const int tlo = q * 128, thi = tlo + 128;
    float* base = C_out + (size_t)b * Sq * NCq + c0;

    for (int t = 0; t < tlo; ++t) {
        int ct = scs[t] - c0; float bv = sbt[t];
        cur0 = (ct == 0) ? bv : cur0;
        cur1 = (ct == 1) ? bv : cur1;
        cur2 = (ct == 2) ? bv : cur2;
        cur3 = (ct == 3) ? bv : cur3;
    }
    for (int t = tlo; t < thi; ++t) {
        int ct = scs[t] - c0; float bv = sbt[t];
        cur0 = (ct == 0) ? bv : cur0;
        cur1 = (ct == 1) ? bv : cur1;
        cur2 = (ct == 2) ? bv : cur2;
        cur3 = (ct == 3) ? bv : cur3;
        *(float4*)(base + (size_t)t * NCq) = make_float4(cur0, cur1, cur2, cur3);
    }
}

// ============ K3: alpha = mlp1(h_seq) ============
__global__ __launch_bounds__(256) void k3_alpha(
    const float* __restrict__ hseq,
    const float* __restrict__ W1, const float* __restrict__ b1,
    const float* __restrict__ W2, const float* __restrict__ b2,
    const float* __restrict__ W3, const float* __restrict__ b3,
    float* __restrict__ alpha_out)
{
    __shared__ float Hs[32 * 128];
    __shared__ float T1[32 * 128];
    __shared__ float red[4][16];
    const int blk = blockIdx.x, tid = threadIdx.x;
    const int row0 = blk * 32;

    for (int e = tid; e < 1024; e += 256) {
        int r = e >> 5, q = e & 31;
        *(float4*)&Hs[r * 128 + 4 * q] =
            *(const float4*)&hseq[(size_t)(row0 + r) * 128 + 4 * q];
    }
    __syncthreads();

    const int j = tid & 127, rh = tid >> 7;
    const float b1j = b1[j], b2j = b2[j], w3j = W3[j];
    float acc[16];
#pragma unroll
    for (int r = 0; r < 16; ++r) acc[r] = b1j;
    for (int k = 0; k < 128; ++k) {
        float w = W1[k * 128 + j];
#pragma unroll
        for (int r = 0; r < 16; ++r)
            acc[r] = fmaf(Hs[(rh * 16 + r) * 128 + k], w, acc[r]);
    }
#pragma unroll
    for (int r = 0; r < 16; ++r) {
        acc[r] = fmaxf(acc[r], 0.f);
        T1[(rh * 16 + r) * 128 + j] = acc[r];
    }
    __syncthreads();
    float acc2[16];
#pragma unroll
    for (int r = 0; r < 16; ++r) acc2[r] = b2j;
    for (int k = 0; k < 128; ++k) {
        float w = W2[k * 128 + j];
#pragma unroll
        for (int r = 0; r < 16; ++r)
            acc2[r] = fmaf(T1[(rh * 16 + r) * 128 + k], w, acc2[r]);
    }
#pragma unroll
    for (int r = 0; r < 16; ++r) {
        float p = fmaxf(acc2[r], 0.f) * w3j;
#pragma unroll
        for (int off = 1; off < 64; off <<= 1) p += __shfl_xor(p, off);
        if ((tid & 63) == 0) red[tid >> 6][r] = p;
    }
    __syncthreads();
    if (tid < 32) {
        int rr = tid & 15, g = tid >> 4;
        alpha_out[row0 + g * 16 + rr] = red[2 * g][rr] + red[2 * g + 1][rr] + b3[0];
    }
}

extern "C" void kernel_launch(void* const* d_in, const int* in_sizes, int n_in,
                              void* d_out, int out_size, void* d_ws, size_t ws_size,
                              hipStream_t stream) {
    const int*   c_seq = (const int*)d_in[0];
    const int*   d_seq = (const int*)d_in[1];
    const float* r_seq = (const float*)d_in[2];
    const float* D1_w  = (const float*)d_in[3];
    const float* D2_w  = (const float*)d_in[4];
    const float* v_r   = (const float*)d_in[5];
    const float* v_b   = (const float*)d_in[6];
    const float* W_ih  = (const float*)d_in[7];
    const float* W_hh  = (const float*)d_in[8];
    const float* b_ih  = (const float*)d_in[9];
    const float* b_hh  = (const float*)d_in[10];
    const float* m1W1  = (const float*)d_in[11];
    const float* m1b1  = (const float*)d_in[12];
    const float* m1W2  = (const float*)d_in[13];
    const float* m1b2  = (const float*)d_in[14];
    const float* m1W3  = (const float*)d_in[15];
    const float* m1b3  = (const float*)d_in[16];
    const float* m2W1  = (const float*)d_in[17];
    const float* m2b1  = (const float*)d_in[18];
    const float* m2W2  = (const float*)d_in[19];
    const float* m2b2  = (const float*)d_in[20];
    const float* m2W3  = (const float*)d_in[21];
    const float* m2b3  = (const float*)d_in[22];

    float* out   = (float*)d_out;
    float* alpha = out;                 // [16*512]
    float* beta  = out + 8192;          // [16*512]
    float* gamma = out + 16384;         // [16*512]
    float* hseq  = out + 24576;         // [16*512*128]
    float* Cseq  = out + 1073152;       // [16*512*10000]
    float* ws    = (float*)d_ws;

    hipLaunchKernelGGL(k0_prep, dim3(161), dim3(256), 0, stream,
                       c_seq, d_seq, D1_w, W_ih, v_r, v_b, m2W1, ws, gamma);
    hipLaunchKernelGGL(k1_gemm, dim3(1024), dim3(256), 0, stream,
                       d_seq, D2_w, m2W1, b_ih, b_hh, r_seq, m2b1, ws);
    hipLaunchKernelGGL(k2_scan, dim3(8), dim3(512), 0, stream,
                       W_hh, b_hh, m2W2, m2b2, m2W3, m2b3, ws, hseq, beta);
    hipLaunchKernelGGL(k2b_fill, dim3(640), dim3(256), 0, stream,
                       c_seq, beta, Cseq);
    hipLaunchKernelGGL(k3_alpha, dim3(256), dim3(256), 0, stream,
                       hseq, m1W1, m1b1, m1W2, m1b2, m1W3, m1b3, alpha);
}

// Round 7
// 636.577 us; speedup vs baseline: 1.8347x; 1.1793x over previous
//
#include <hip/hip_runtime.h>

#define Bq   16
#define Sq   512
#define Vq   128
#define NCq  10000

typedef __attribute__((ext_vector_type(8))) short short8v;
typedef __attribute__((ext_vector_type(4))) float f32x4;

// ---- workspace layout ----
// ushort region (from ws base):
//   XPB:  [4 bg][512 t][96 r4][4 b][4 e] bf16, 3,145,728 ushorts
//   P1B:  [512 t][16 b][128 j] bf16,        1,048,576 ushorts
#define OFF_P1B_U  3145728u
// float offsets:
#define OFF_WTIH   2097152u    // [128 k][384 g] W_ih[:, :V]^T
#define OFF_WVRIH  2146304u    // [384]
#define OFF_WVR1   2146688u    // [128]
#define OFF_WVB    2146816u    // [128]
#define OFF_PO     2146944u    // int [512 t][16 b]

#define PLN 136
#define PLSZ (16*PLN+8)

__device__ __forceinline__ unsigned short f2bf(float x) {
    unsigned u = __builtin_bit_cast(unsigned, x);
    unsigned r = (u + 0x7fffu + ((u >> 16) & 1u)) >> 16;
    return (unsigned short)r;
}
__device__ __forceinline__ float bfhi(unsigned u) {
    return __builtin_bit_cast(float, u << 16);
}
__device__ __forceinline__ float bflo(unsigned u) {
    return __builtin_bit_cast(float, u & 0xffff0000u);
}
__device__ __forceinline__ void barrier_lgkm() {
    asm volatile("s_waitcnt lgkmcnt(0)" ::: "memory");
    __builtin_amdgcn_sched_barrier(0);
    __builtin_amdgcn_s_barrier();
    __builtin_amdgcn_sched_barrier(0);
}

// ============ K0: transpose, small vectors, prev-occurrence, gamma ============
__global__ __launch_bounds__(256) void k0_prep(
    const int* __restrict__ c_seq, const int* __restrict__ d_seq,
    const float* __restrict__ D1_w,
    const float* __restrict__ W_ih,
    const float* __restrict__ v_r, const float* __restrict__ v_beta,
    const float* __restrict__ m2W1,
    float* __restrict__ ws, float* __restrict__ gamma_out)
{
    const int blk = blockIdx.x, tid = threadIdx.x;

    if (blk < 128) {
        float* WTIH = ws + OFF_WTIH;
        int base = blk * 384;
        for (int i = tid; i < 384; i += 256) {
            int e = base + i;
            int k = e / 384, g = e % 384;
            WTIH[e] = W_ih[g * 256 + k];
        }
    } else if (blk == 128) {
        float* WVRIH = ws + OFF_WVRIH;
        float* WVR1  = ws + OFF_WVR1;
        float* WVB   = ws + OFF_WVB;
        for (int g = tid; g < 384; g += 256) {
            float a = 0.f;
            for (int k = 0; k < 128; ++k) a = fmaf(v_r[k], W_ih[g * 256 + 128 + k], a);
            WVRIH[g] = a;
        }
        if (tid < 128) {
            float a = 0.f, b = 0.f;
            for (int k = 0; k < 128; ++k) {
                a = fmaf(v_r[k],    m2W1[(256 + k) * 128 + tid], a);
                b = fmaf(v_beta[k], m2W1[k * 128 + tid],         b);
            }
            WVR1[tid] = a; WVB[tid] = b;
        }
    } else if (blk < 145) {
        const int b = blk - 129;
        __shared__ int cs[Sq];
        for (int i = tid; i < Sq; i += 256) cs[i] = c_seq[b * Sq + i];
        __syncthreads();
        int* PO = (int*)(ws + OFF_PO);
        for (int t = tid; t < Sq; t += 256) {
            int c = cs[t];
            int po = -1;
            for (int u = t - 1; u >= 0; --u) if (cs[u] == c) { po = u; break; }
            PO[t * 16 + b] = po;
        }
    } else {
        const int b = blk - 145;
        for (int s = tid; s < Sq; s += 256)
            gamma_out[b * Sq + s] = D1_w[d_seq[b * Sq + s]];
    }
}

// ============ K1: batched GEMM -> xpb (bf16) | p1b (bf16), biases folded ============
__global__ __launch_bounds__(256) void k1_gemm(
    const int* __restrict__ d_seq, const float* __restrict__ D2_w,
    const float* __restrict__ m2W1,
    const float* __restrict__ b_ih, const float* __restrict__ b_hh,
    const float* __restrict__ r_seq, const float* __restrict__ m2b1,
    float* __restrict__ ws)
{
    __shared__ float As[64 * 128];
    __shared__ float Bs[128 * 64];
    const int blk = blockIdx.x, tid = threadIdx.x;
    const int nc = blk & 7;
    const int m0 = (blk >> 3) * 64;
    const float* WTIH = ws + OFF_WTIH;

    const float4* D2v = (const float4*)D2_w;
    for (int e = tid; e < 2048; e += 256) {
        int r = e >> 5, q = e & 31;
        int d = d_seq[m0 + r];
        *(float4*)&As[r * 128 + 4 * q] = D2v[d * 32 + q];
    }
    for (int e = tid; e < 2048; e += 256) {
        int k = e >> 4, q = e & 15;
        float4 v;
        if (nc < 6) v = *(const float4*)&WTIH[k * 384 + nc * 64 + 4 * q];
        else        v = *(const float4*)&m2W1[(128 + k) * 128 + (nc - 6) * 64 + 4 * q];
        *(float4*)&Bs[k * 64 + 4 * q] = v;
    }
    __syncthreads();

    const int tx = tid & 15, ty = tid >> 4;
    const int c0 = 4 * tx, r0 = 4 * ty;
    float acc[4][4];
#pragma unroll
    for (int i = 0; i < 4; ++i)
#pragma unroll
        for (int j = 0; j < 4; ++j) acc[i][j] = 0.f;

    for (int k = 0; k < 128; ++k) {
        float4 bv = *(const float4*)&Bs[k * 64 + c0];
#pragma unroll
        for (int i = 0; i < 4; ++i) {
            float a = As[(r0 + i) * 128 + k];
            acc[i][0] = fmaf(a, bv.x, acc[i][0]);
            acc[i][1] = fmaf(a, bv.y, acc[i][1]);
            acc[i][2] = fmaf(a, bv.z, acc[i][2]);
            acc[i][3] = fmaf(a, bv.w, acc[i][3]);
        }
    }

    float rsv[4];
#pragma unroll
    for (int i = 0; i < 4; ++i) rsv[i] = r_seq[m0 + r0 + i];

    if (nc < 6) {
        const int grow0 = nc * 64 + c0;
        float4 bi  = *(const float4*)&b_ih[grow0];
        float4 wv4 = *(const float4*)&(ws + OFF_WVRIH)[grow0];
        float4 bh4 = make_float4(0.f, 0.f, 0.f, 0.f);
        if (nc < 4) bh4 = *(const float4*)&b_hh[grow0];
        unsigned short* XPB = (unsigned short*)ws;
        const int r4 = grow0 >> 2;
#pragma unroll
        for (int i = 0; i < 4; ++i) {
            int row = m0 + r0 + i;
            int t = row & 511, bb = row >> 9;
            float vx = acc[i][0] + bi.x + bh4.x + rsv[i] * wv4.x;
            float vy = acc[i][1] + bi.y + bh4.y + rsv[i] * wv4.y;
            float vz = acc[i][2] + bi.z + bh4.z + rsv[i] * wv4.z;
            float vw = acc[i][3] + bi.w + bh4.w + rsv[i] * wv4.w;
            uint2 p;
            p.x = (unsigned)f2bf(vx) | ((unsigned)f2bf(vy) << 16);
            p.y = (unsigned)f2bf(vz) | ((unsigned)f2bf(vw) << 16);
            *(uint2*)&XPB[((size_t)((bb >> 2) * 512 + t)) * 1536 + r4 * 16 + (bb & 3) * 4] = p;
        }
    } else {
        const int j0 = (nc - 6) * 64 + c0;
        float4 b1v = *(const float4*)&m2b1[j0];
        float4 wr1 = *(const float4*)&(ws + OFF_WVR1)[j0];
        unsigned short* P1B = (unsigned short*)ws + OFF_P1B_U;
#pragma unroll
        for (int i = 0; i < 4; ++i) {
            int row = m0 + r0 + i;
            int t = row & 511, bb = row >> 9;
            float vx = acc[i][0] + b1v.x + rsv[i] * wr1.x;
            float vy = acc[i][1] + b1v.y + rsv[i] * wr1.y;
            float vz = acc[i][2] + b1v.z + rsv[i] * wr1.z;
            float vw = acc[i][3] + b1v.w + rsv[i] * wr1.w;
            uint2 p;
            p.x = (unsigned)f2bf(vx) | ((unsigned)f2bf(vy) << 16);
            p.y = (unsigned)f2bf(vz) | ((unsigned)f2bf(vw) << 16);
            *(uint2*)&P1B[((size_t)(t * 16 + bb)) * 128 + j0] = p;
        }
    }
}

// ============ K2: 8 blocks. blk 0..3: GRU (4 batches). blk 4..7: beta (4 batches) ============
__global__ __launch_bounds__(512, 1) void k2_scan(
    const float* __restrict__ W_hh, const float* __restrict__ b_hh,
    const float* __restrict__ m2W2, const float* __restrict__ m2b2,
    const float* __restrict__ m2W3, const float* __restrict__ m2b3,
    float* __restrict__ ws,
    float* __restrict__ hseq_out, float* __restrict__ beta_out)
{
    __shared__ __align__(16) unsigned char smem[12800];
    const int tid = threadIdx.x;
    const int l = tid & 63, wv = tid >> 6;
    const int qq = l >> 4, cb = l & 15;
    const int bgid = blockIdx.x;

    if (bgid < 4) {
        // ---------------- GRU, batches 4*bgid .. 4*bgid+3 ----------------
        unsigned short* hP = (unsigned short*)smem;          // [2][PLSZ]
        const unsigned short* XPB = (const unsigned short*)ws;

        short8v aH0[4], aH1[4], aH2[4];
#pragma unroll
        for (int kf = 0; kf < 4; ++kf) {
            const int kb = kf * 32 + qq * 8;
            const float* w0 = W_hh + (0 * 128 + 16 * wv + cb) * 128 + kb;
            const float* w1 = W_hh + (1 * 128 + 16 * wv + cb) * 128 + kb;
            const float* w2 = W_hh + (2 * 128 + 16 * wv + cb) * 128 + kb;
            short8v h0, h1, h2;
#pragma unroll
            for (int e = 0; e < 8; ++e) {
                h0[e] = (short)f2bf(w0[e]);
                h1[e] = (short)f2bf(w1[e]);
                h2[e] = (short)f2bf(w2[e]);
            }
            aH0[kf] = h0; aH1[kf] = h1; aH2[kf] = h2;
        }
        float bhn[4];
        *(float4*)bhn = *(const float4*)&b_hh[256 + 16 * wv + 4 * qq];

        const size_t pbase = (size_t)(bgid * 512) * 1536 + (4 * wv + qq) * 16 + (cb & 3) * 4;
        uint2 pxA0 = *(const uint2*)(XPB + pbase);
        uint2 pxA1 = *(const uint2*)(XPB + pbase + 512);
        uint2 pxA2 = *(const uint2*)(XPB + pbase + 1024);
        uint2 pxB0 = *(const uint2*)(XPB + pbase + 1536);
        uint2 pxB1 = *(const uint2*)(XPB + pbase + 1536 + 512);
        uint2 pxB2 = *(const uint2*)(XPB + pbase + 1536 + 1024);

        float* hp = hseq_out + ((size_t)((bgid * 4 + (cb & 3)) * 512)) * 128 + 16 * wv + 4 * qq;
        float hold[4] = {0.f, 0.f, 0.f, 0.f};
        for (int i = tid; i < 2 * PLSZ; i += 512) hP[i] = 0;
        __syncthreads();

        for (int t = 0; t < 512; ++t) {
            float pf0[4] = {bfhi(pxA0.x), bflo(pxA0.x), bfhi(pxA0.y), bflo(pxA0.y)};
            float pf1[4] = {bfhi(pxA1.x), bflo(pxA1.x), bfhi(pxA1.y), bflo(pxA1.y)};
            float pf2[4] = {bfhi(pxA2.x), bflo(pxA2.x), bfhi(pxA2.y), bflo(pxA2.y)};
            pxA0 = pxB0; pxA1 = pxB1; pxA2 = pxB2;
            if (t < 510) {
                const unsigned short* s = XPB + pbase + (size_t)(t + 2) * 1536;
                pxB0 = *(const uint2*)(s);
                pxB1 = *(const uint2*)(s + 512);
                pxB2 = *(const uint2*)(s + 1024);
            }
            const unsigned short* HI = hP + (t & 1) * PLSZ;
            unsigned short* HIn = hP + ((t + 1) & 1) * PLSZ;

            f32x4 C0 = {0.f,0.f,0.f,0.f}, C1 = {0.f,0.f,0.f,0.f}, C2 = {0.f,0.f,0.f,0.f};
#pragma unroll
            for (int kf = 0; kf < 4; ++kf) {
                short8v Bh = *(const short8v*)(HI + cb * PLN + kf * 32 + qq * 8);
                C0 = __builtin_amdgcn_mfma_f32_16x16x32_bf16(aH0[kf], Bh, C0, 0, 0, 0);
                C1 = __builtin_amdgcn_mfma_f32_16x16x32_bf16(aH1[kf], Bh, C1, 0, 0, 0);
                C2 = __builtin_amdgcn_mfma_f32_16x16x32_bf16(aH2[kf], Bh, C2, 0, 0, 0);
            }
            float hnew[4];
#pragma unroll
            for (int i = 0; i < 4; ++i) {
                float pr = C0[i] + pf0[i];
                float pz = C1[i] + pf1[i];
                float r = __builtin_amdgcn_rcpf(1.f + __expf(-pr));
                float z = __builtin_amdgcn_rcpf(1.f + __expf(-pz));
                float hn = C2[i] + bhn[i];
                float npre = fmaf(r, hn, pf2[i]);
                float e2 = __expf(-2.f * fabsf(npre));
                float n = copysignf((1.f - e2) * __builtin_amdgcn_rcpf(1.f + e2), npre);
                float hv = fmaf(z, hold[i] - n, n);
                hold[i] = hv;
                hnew[i] = hv;
            }
            if (cb < 4) {
                *(float4*)hp = make_float4(hnew[0], hnew[1], hnew[2], hnew[3]);
                uint2 hw;
                hw.x = (unsigned)f2bf(hnew[0]) | ((unsigned)f2bf(hnew[1]) << 16);
                hw.y = (unsigned)f2bf(hnew[2]) | ((unsigned)f2bf(hnew[3]) << 16);
                *(uint2*)(HIn + cb * PLN + 16 * wv + 4 * qq) = hw;
            }
            hp += 128;
            barrier_lgkm();
        }
    } else {
        // ---------------- beta scan, batches 4*bq .. 4*bq+3 ----------------
        const int bq = bgid - 4;
        float* bhL = (float*)smem;                                 // [4][512] 8KB
        unsigned short* h1P = (unsigned short*)(smem + 8192);      // [PLSZ]
        float* redT = (float*)(smem + 8192 + 2 * PLSZ);            // [4][8]
        const unsigned short* P1B = (const unsigned short*)ws + OFF_P1B_U;
        const int* POg = (const int*)(ws + OFF_PO);

        short8v aH[4];
#pragma unroll
        for (int kf = 0; kf < 4; ++kf) {
            short8v hi;
#pragma unroll
            for (int e = 0; e < 8; ++e)
                hi[e] = (short)f2bf(m2W2[(kf * 32 + qq * 8 + e) * 128 + 16 * wv + cb]);
            aH[kf] = hi;
        }
        float w3C[4], b2C[4];
        *(float4*)w3C = *(const float4*)&m2W3[16 * wv + 4 * qq];
        *(float4*)b2C = *(const float4*)&m2b2[16 * wv + 4 * qq];
        const float b3v = m2b3[0];

        const bool pa = (tid < 128);
        const int bb2 = tid & 3, j4 = (tid >> 2) & 31;
        float wvb[4] = {0.f, 0.f, 0.f, 0.f};
        uint2 p1A = {0, 0}, p1B = {0, 0};
        int poCur = -1, poNxt = -1;
        float bpPre = 0.f, btap = 0.f;
        if (pa) {
            *(float4*)wvb = *(const float4*)&(ws + OFF_WVB)[j4 * 4];
            p1A = *(const uint2*)(P1B + (size_t)(0 * 16 + 4 * bq + bb2) * 128 + j4 * 4);
            p1B = *(const uint2*)(P1B + (size_t)(1 * 16 + 4 * bq + bb2) * 128 + j4 * 4);
            poCur = POg[0 * 16 + 4 * bq + bb2];
            poNxt = POg[1 * 16 + 4 * bq + bb2];
        }
        for (int i = tid; i < PLSZ; i += 512) h1P[i] = 0;
        __syncthreads();

        for (int t = 0; t < 512; ++t) {
            if (pa) {
                float bp = (poCur == t - 1) ? btap : bpPre;
                float f0 = bfhi(p1A.x), f1 = bflo(p1A.x);
                float f2v = bfhi(p1A.y), f3 = bflo(p1A.y);
                float h0 = fmaxf(0.f, fmaf(bp, wvb[0], f0));
                float h1 = fmaxf(0.f, fmaf(bp, wvb[1], f1));
                float h2 = fmaxf(0.f, fmaf(bp, wvb[2], f2v));
                float h3 = fmaxf(0.f, fmaf(bp, wvb[3], f3));
                uint2 hw;
                hw.x = (unsigned)f2bf(h0) | ((unsigned)f2bf(h1) << 16);
                hw.y = (unsigned)f2bf(h2) | ((unsigned)f2bf(h3) << 16);
                *(uint2*)(h1P + bb2 * PLN + j4 * 4) = hw;
                p1A = p1B;
                if (t < 510)
                    p1B = *(const uint2*)(P1B + (size_t)((t + 2) * 16 + 4 * bq + bb2) * 128 + j4 * 4);
            }
            barrier_lgkm();   // barrier 1: planes ready

            if (pa) {
                bpPre = 0.f;
                if (poNxt >= 0 && poNxt < t) bpPre = bhL[bb2 * 512 + poNxt];
                poCur = poNxt;
                if (t < 510) poNxt = POg[(t + 2) * 16 + 4 * bq + bb2];
            }
            f32x4 C = {0.f, 0.f, 0.f, 0.f};
#pragma unroll
            for (int kf = 0; kf < 4; ++kf) {
                short8v Bh = *(const short8v*)(h1P + cb * PLN + kf * 32 + qq * 8);
                C = __builtin_amdgcn_mfma_f32_16x16x32_bf16(aH[kf], Bh, C, 0, 0, 0);
            }
            float part = 0.f;
#pragma unroll
            for (int i = 0; i < 4; ++i)
                part = fmaf(fmaxf(0.f, C[i] + b2C[i]), w3C[i], part);
            part += __shfl_xor(part, 16);
            part += __shfl_xor(part, 32);
            if (qq == 0 && cb < 4) redT[cb * 8 + wv] = part;
            barrier_lgkm();   // barrier 2: redT ready

            if (pa) {
                float4 ra = *(const float4*)&redT[bb2 * 8];
                float4 rb = *(const float4*)&redT[bb2 * 8 + 4];
                float bta = ((ra.x + ra.y) + (ra.z + ra.w)) +
                            ((rb.x + rb.y) + (rb.z + rb.w)) + b3v;
                if (j4 == 0) bhL[bb2 * 512 + t] = bta;
                btap = bta;
            }
        }
        __syncthreads();
        for (int i = tid; i < 2048; i += 512)
            beta_out[(4 * bq + (i >> 9)) * 512 + (i & 511)] = bhL[i];
    }
}

// ============ K2b: dense C fill (zeros + latest-occurrence betas) ============
__global__ __launch_bounds__(256) void k2b_fill(
    const int* __restrict__ c_seq, const float* __restrict__ beta_in,
    float* __restrict__ C_out)
{
    __shared__ int   scs[Sq];
    __shared__ float sbt[Sq];
    const int bid = blockIdx.x, tid = threadIdx.x;
    const int b = bid / 40, rem = bid % 40;
    const int chunk = rem >> 2, q = rem & 3;

    for (int i = tid; i < Sq; i += 256) {
        scs[i] = c_seq[b * Sq + i];
        sbt[i] = beta_in[b * Sq + i];
    }
    __syncthreads();

    const int c0 = chunk * 1024 + tid * 4;
    if (c0 >= NCq) return;

    float cur0 = 0.f, cur1 = 0.f, cur2 = 0.f, cur3 = 0.f;
    const int tlo = q * 128, thi = tlo + 128;
    float* base = C_out + (size_t)b * Sq * NCq + c0;

    for (int t = 0; t < tlo; ++t) {
        int ct = scs[t] - c0; float bv = sbt[t];
        cur0 = (ct == 0) ? bv : cur0;
        cur1 = (ct == 1) ? bv : cur1;
        cur2 = (ct == 2) ? bv : cur2;
        cur3 = (ct == 3) ? bv : cur3;
    }
    for (int t = tlo; t < thi; ++t) {
        int ct = scs[t] - c0; float bv = sbt[t];
        cur0 = (ct == 0) ? bv : cur0;
        cur1 = (ct == 1) ? bv : cur1;
        cur2 = (ct == 2) ? bv : cur2;
        cur3 = (ct == 3) ? bv : cur3;
        *(float4*)(base + (size_t)t * NCq) = make_float4(cur0, cur1, cur2, cur3);
    }
}

// ============ K3: alpha = mlp1(h_seq) ============
__global__ __launch_bounds__(256) void k3_alpha(
    const float* __restrict__ hseq,
    const float* __restrict__ W1, const float* __restrict__ b1,
    const float* __restrict__ W2, const float* __restrict__ b2,
    const float* __restrict__ W3, const float* __restrict__ b3,
    float* __restrict__ alpha_out)
{
    __shared__ float Hs[32 * 128];
    __shared__ float T1[32 * 128];
    __shared__ float red[4][16];
    const int blk = blockIdx.x, tid = threadIdx.x;
    const int row0 = blk * 32;

    for (int e = tid; e < 1024; e += 256) {
        int r = e >> 5, q = e & 31;
        *(float4*)&Hs[r * 128 + 4 * q] =
            *(const float4*)&hseq[(size_t)(row0 + r) * 128 + 4 * q];
    }
    __syncthreads();

    const int j = tid & 127, rh = tid >> 7;
    const float b1j = b1[j], b2j = b2[j], w3j = W3[j];
    float acc[16];
#pragma unroll
    for (int r = 0; r < 16; ++r) acc[r] = b1j;
    for (int k = 0; k < 128; ++k) {
        float w = W1[k * 128 + j];
#pragma unroll
        for (int r = 0; r < 16; ++r)
            acc[r] = fmaf(Hs[(rh * 16 + r) * 128 + k], w, acc[r]);
    }
#pragma unroll
    for (int r = 0; r < 16; ++r) {
        acc[r] = fmaxf(acc[r], 0.f);
        T1[(rh * 16 + r) * 128 + j] = acc[r];
    }
    __syncthreads();
    float acc2[16];
#pragma unroll
    for (int r = 0; r < 16; ++r) acc2[r] = b2j;
    for (int k = 0; k < 128; ++k) {
        float w = W2[k * 128 + j];
#pragma unroll
        for (int r = 0; r < 16; ++r)
            acc2[r] = fmaf(T1[(rh * 16 + r) * 128 + k], w, acc2[r]);
    }
#pragma unroll
    for (int r = 0; r < 16; ++r) {
        float p = fmaxf(acc2[r], 0.f) * w3j;
#pragma unroll
        for (int off = 1; off < 64; off <<= 1) p += __shfl_xor(p, off);
        if ((tid & 63) == 0) red[tid >> 6][r] = p;
    }
    __syncthreads();
    if (tid < 32) {
        int rr = tid & 15, g = tid >> 4;
        alpha_out[row0 + g * 16 + rr] = red[2 * g][rr] + red[2 * g + 1][rr] + b3[0];
    }
}

extern "C" void kernel_launch(void* const* d_in, const int* in_sizes, int n_in,
                              void* d_out, int out_size, void* d_ws, size_t ws_size,
                              hipStream_t stream) {
    const int*   c_seq = (const int*)d_in[0];
    const int*   d_seq = (const int*)d_in[1];
    const float* r_seq = (const float*)d_in[2];
    const float* D1_w  = (const float*)d_in[3];
    const float* D2_w  = (const float*)d_in[4];
    const float* v_r   = (const float*)d_in[5];
    const float* v_b   = (const float*)d_in[6];
    const float* W_ih  = (const float*)d_in[7];
    const float* W_hh  = (const float*)d_in[8];
    const float* b_ih  = (const float*)d_in[9];
    const float* b_hh  = (const float*)d_in[10];
    const float* m1W1  = (const float*)d_in[11];
    const float* m1b1  = (const float*)d_in[12];
    const float* m1W2  = (const float*)d_in[13];
    const float* m1b2  = (const float*)d_in[14];
    const float* m1W3  = (const float*)d_in[15];
    const float* m1b3  = (const float*)d_in[16];
    const float* m2W1  = (const float*)d_in[17];
    const float* m2b1  = (const float*)d_in[18];
    const float* m2W2  = (const float*)d_in[19];
    const float* m2b2  = (const float*)d_in[20];
    const float* m2W3  = (const float*)d_in[21];
    const float* m2b3  = (const float*)d_in[22];

    float* out   = (float*)d_out;
    float* alpha = out;                 // [16*512]
    float* beta  = out + 8192;          // [16*512]
    float* gamma = out + 16384;         // [16*512]
    float* hseq  = out + 24576;         // [16*512*128]
    float* Cseq  = out + 1073152;       // [16*512*10000]
    float* ws    = (float*)d_ws;

    hipLaunchKernelGGL(k0_prep, dim3(161), dim3(256), 0, stream,
                       c_seq, d_seq, D1_w, W_ih, v_r, v_b, m2W1, ws, gamma);
    hipLaunchKernelGGL(k1_gemm, dim3(1024), dim3(256), 0, stream,
                       d_seq, D2_w, m2W1, b_ih, b_hh, r_seq, m2b1, ws);
    hipLaunchKernelGGL(k2_scan, dim3(8), dim3(512), 0, stream,
                       W_hh, b_hh, m2W2, m2b2, m2W3, m2b3, ws, hseq, beta);
    hipLaunchKernelGGL(k2b_fill, dim3(640), dim3(256), 0, stream,
                       c_seq, beta, Cseq);
    hipLaunchKernelGGL(k3_alpha, dim3(256), dim3(256), 0, stream,
                       hseq, m1W1, m1b1, m1W2, m1b2, m1W3, m1b3, alpha);
}

// Round 8
// 630.372 us; speedup vs baseline: 1.8528x; 1.0098x over previous
//
#include <hip/hip_runtime.h>

#define Bq   16
#define Sq   512
#define Vq   128
#define NCq  10000

typedef __attribute__((ext_vector_type(8))) short short8v;
typedef __attribute__((ext_vector_type(4))) float f32x4;

// ---- workspace layout ----
// ushort region (from ws base):
//   XPB:  [4 bg][512 t][96 r4][4 b][4 e] bf16, 3,145,728 ushorts
//   P1B:  [512 t][16 b][128 j] bf16,        1,048,576 ushorts
#define OFF_P1B_U  3145728u
// float offsets:
#define OFF_WTIH   2097152u    // [128 k][384 g] W_ih[:, :V]^T
#define OFF_WVRIH  2146304u    // [384]
#define OFF_WVR1   2146688u    // [128]
#define OFF_WVB    2146816u    // [128]
#define OFF_PO     2146944u    // int [512 t][16 b]

#define PLN 136
#define PLSZ (16*PLN+8)

__device__ __forceinline__ unsigned short f2bf(float x) {
    unsigned u = __builtin_bit_cast(unsigned, x);
    unsigned r = (u + 0x7fffu + ((u >> 16) & 1u)) >> 16;
    return (unsigned short)r;
}
__device__ __forceinline__ float bfhi(unsigned u) {
    return __builtin_bit_cast(float, u << 16);
}
__device__ __forceinline__ float bflo(unsigned u) {
    return __builtin_bit_cast(float, u & 0xffff0000u);
}
__device__ __forceinline__ void barrier_lgkm() {
    asm volatile("s_waitcnt lgkmcnt(0)" ::: "memory");
    __builtin_amdgcn_sched_barrier(0);
    __builtin_amdgcn_s_barrier();
    __builtin_amdgcn_sched_barrier(0);
}
__device__ __forceinline__ void wait_vm0() {
    asm volatile("s_waitcnt vmcnt(0)" ::: "memory");
    __builtin_amdgcn_sched_barrier(0);
}
__device__ __forceinline__ void gload_lds16(const void* g, void* l) {
    __builtin_amdgcn_global_load_lds(
        (const __attribute__((address_space(1))) unsigned int*)g,
        (__attribute__((address_space(3))) unsigned int*)l, 16, 0, 0);
}

// ============ K0: transpose, small vectors, prev-occurrence, gamma ============
__global__ __launch_bounds__(256) void k0_prep(
    const int* __restrict__ c_seq, const int* __restrict__ d_seq,
    const float* __restrict__ D1_w,
    const float* __restrict__ W_ih,
    const float* __restrict__ v_r, const float* __restrict__ v_beta,
    const float* __restrict__ m2W1,
    float* __restrict__ ws, float* __restrict__ gamma_out)
{
    const int blk = blockIdx.x, tid = threadIdx.x;

    if (blk < 128) {
        float* WTIH = ws + OFF_WTIH;
        int base = blk * 384;
        for (int i = tid; i < 384; i += 256) {
            int e = base + i;
            int k = e / 384, g = e % 384;
            WTIH[e] = W_ih[g * 256 + k];
        }
    } else if (blk == 128) {
        float* WVRIH = ws + OFF_WVRIH;
        float* WVR1  = ws + OFF_WVR1;
        float* WVB   = ws + OFF_WVB;
        for (int g = tid; g < 384; g += 256) {
            float a = 0.f;
            for (int k = 0; k < 128; ++k) a = fmaf(v_r[k], W_ih[g * 256 + 128 + k], a);
            WVRIH[g] = a;
        }
        if (tid < 128) {
            float a = 0.f, b = 0.f;
            for (int k = 0; k < 128; ++k) {
                a = fmaf(v_r[k],    m2W1[(256 + k) * 128 + tid], a);
                b = fmaf(v_beta[k], m2W1[k * 128 + tid],         b);
            }
            WVR1[tid] = a; WVB[tid] = b;
        }
    } else if (blk < 145) {
        const int b = blk - 129;
        __shared__ int cs[Sq];
        for (int i = tid; i < Sq; i += 256) cs[i] = c_seq[b * Sq + i];
        __syncthreads();
        int* PO = (int*)(ws + OFF_PO);
        for (int t = tid; t < Sq; t += 256) {
            int c = cs[t];
            int po = -1;
            for (int u = t - 1; u >= 0; --u) if (cs[u] == c) { po = u; break; }
            PO[t * 16 + b] = po;
        }
    } else {
        const int b = blk - 145;
        for (int s = tid; s < Sq; s += 256)
            gamma_out[b * Sq + s] = D1_w[d_seq[b * Sq + s]];
    }
}

// ============ K1: batched GEMM -> xpb (bf16) | p1b (bf16), biases folded ============
__global__ __launch_bounds__(256) void k1_gemm(
    const int* __restrict__ d_seq, const float* __restrict__ D2_w,
    const float* __restrict__ m2W1,
    const float* __restrict__ b_ih, const float* __restrict__ b_hh,
    const float* __restrict__ r_seq, const float* __restrict__ m2b1,
    float* __restrict__ ws)
{
    __shared__ float As[64 * 128];
    __shared__ float Bs[128 * 64];
    const int blk = blockIdx.x, tid = threadIdx.x;
    const int nc = blk & 7;
    const int m0 = (blk >> 3) * 64;
    const float* WTIH = ws + OFF_WTIH;

    const float4* D2v = (const float4*)D2_w;
    for (int e = tid; e < 2048; e += 256) {
        int r = e >> 5, q = e & 31;
        int d = d_seq[m0 + r];
        *(float4*)&As[r * 128 + 4 * q] = D2v[d * 32 + q];
    }
    for (int e = tid; e < 2048; e += 256) {
        int k = e >> 4, q = e & 15;
        float4 v;
        if (nc < 6) v = *(const float4*)&WTIH[k * 384 + nc * 64 + 4 * q];
        else        v = *(const float4*)&m2W1[(128 + k) * 128 + (nc - 6) * 64 + 4 * q];
        *(float4*)&Bs[k * 64 + 4 * q] = v;
    }
    __syncthreads();

    const int tx = tid & 15, ty = tid >> 4;
    const int c0 = 4 * tx, r0 = 4 * ty;
    float acc[4][4];
#pragma unroll
    for (int i = 0; i < 4; ++i)
#pragma unroll
        for (int j = 0; j < 4; ++j) acc[i][j] = 0.f;

    for (int k = 0; k < 128; ++k) {
        float4 bv = *(const float4*)&Bs[k * 64 + c0];
#pragma unroll
        for (int i = 0; i < 4; ++i) {
            float a = As[(r0 + i) * 128 + k];
            acc[i][0] = fmaf(a, bv.x, acc[i][0]);
            acc[i][1] = fmaf(a, bv.y, acc[i][1]);
            acc[i][2] = fmaf(a, bv.z, acc[i][2]);
            acc[i][3] = fmaf(a, bv.w, acc[i][3]);
        }
    }

    float rsv[4];
#pragma unroll
    for (int i = 0; i < 4; ++i) rsv[i] = r_seq[m0 + r0 + i];

    if (nc < 6) {
        const int grow0 = nc * 64 + c0;
        float4 bi  = *(const float4*)&b_ih[grow0];
        float4 wv4 = *(const float4*)&(ws + OFF_WVRIH)[grow0];
        float4 bh4 = make_float4(0.f, 0.f, 0.f, 0.f);
        if (nc < 4) bh4 = *(const float4*)&b_hh[grow0];
        unsigned short* XPB = (unsigned short*)ws;
        const int r4 = grow0 >> 2;
#pragma unroll
        for (int i = 0; i < 4; ++i) {
            int row = m0 + r0 + i;
            int t = row & 511, bb = row >> 9;
            float vx = acc[i][0] + bi.x + bh4.x + rsv[i] * wv4.x;
            float vy = acc[i][1] + bi.y + bh4.y + rsv[i] * wv4.y;
            float vz = acc[i][2] + bi.z + bh4.z + rsv[i] * wv4.z;
            float vw = acc[i][3] + bi.w + bh4.w + rsv[i] * wv4.w;
            uint2 p;
            p.x = (unsigned)f2bf(vx) | ((unsigned)f2bf(vy) << 16);
            p.y = (unsigned)f2bf(vz) | ((unsigned)f2bf(vw) << 16);
            *(uint2*)&XPB[((size_t)((bb >> 2) * 512 + t)) * 1536 + r4 * 16 + (bb & 3) * 4] = p;
        }
    } else {
        const int j0 = (nc - 6) * 64 + c0;
        float4 b1v = *(const float4*)&m2b1[j0];
        float4 wr1 = *(const float4*)&(ws + OFF_WVR1)[j0];
        unsigned short* P1B = (unsigned short*)ws + OFF_P1B_U;
#pragma unroll
        for (int i = 0; i < 4; ++i) {
            int row = m0 + r0 + i;
            int t = row & 511, bb = row >> 9;
            float vx = acc[i][0] + b1v.x + rsv[i] * wr1.x;
            float vy = acc[i][1] + b1v.y + rsv[i] * wr1.y;
            float vz = acc[i][2] + b1v.z + rsv[i] * wr1.z;
            float vw = acc[i][3] + b1v.w + rsv[i] * wr1.w;
            uint2 p;
            p.x = (unsigned)f2bf(vx) | ((unsigned)f2bf(vy) << 16);
            p.y = (unsigned)f2bf(vz) | ((unsigned)f2bf(vw) << 16);
            *(uint2*)&P1B[((size_t)(t * 16 + bb)) * 128 + j0] = p;
        }
    }
}

// ============ K2: 8 blocks. blk 0..3: GRU (4 batches). blk 4..7: beta (4 batches) ============
// XP/PRE1 staged into LDS in 8-step double-buffered chunks via global_load_lds;
// vmcnt(0) folded into the once-per-8-steps barrier.
__global__ __launch_bounds__(512, 1) void k2_scan(
    const float* __restrict__ W_hh, const float* __restrict__ b_hh,
    const float* __restrict__ m2W2, const float* __restrict__ m2b2,
    const float* __restrict__ m2W3, const float* __restrict__ m2b3,
    float* __restrict__ ws,
    float* __restrict__ hseq_out, float* __restrict__ beta_out)
{
    __shared__ __align__(16) unsigned char smem[57984];
    const int tid = threadIdx.x;
    const int l = tid & 63, wv = tid >> 6;
    const int qq = l >> 4, cb = l & 15;
    const int bgid = blockIdx.x;

    if (bgid < 4) {
        // ---------------- GRU, batches 4*bgid .. 4*bgid+3 ----------------
        unsigned short* hP  = (unsigned short*)smem;               // [2][PLSZ]
        unsigned short* xch = (unsigned short*)(smem + 8736);      // 2 x 12288 ushorts
        const unsigned short* XPB = (const unsigned short*)ws;

        short8v aH0[4], aH1[4], aH2[4];
#pragma unroll
        for (int kf = 0; kf < 4; ++kf) {
            const int kb = kf * 32 + qq * 8;
            const float* w0 = W_hh + (0 * 128 + 16 * wv + cb) * 128 + kb;
            const float* w1 = W_hh + (1 * 128 + 16 * wv + cb) * 128 + kb;
            const float* w2 = W_hh + (2 * 128 + 16 * wv + cb) * 128 + kb;
            short8v h0, h1, h2;
#pragma unroll
            for (int e = 0; e < 8; ++e) {
                h0[e] = (short)f2bf(w0[e]);
                h1[e] = (short)f2bf(w1[e]);
                h2[e] = (short)f2bf(w2[e]);
            }
            aH0[kf] = h0; aH1[kf] = h1; aH2[kf] = h2;
        }
        float bhn[4];
        *(float4*)bhn = *(const float4*)&b_hh[256 + 16 * wv + 4 * qq];

        float* hp = hseq_out + ((size_t)((bgid * 4 + (cb & 3)) * 512)) * 128 + 16 * wv + 4 * qq;
        float hold[4] = {0.f, 0.f, 0.f, 0.f};
        for (int i = tid; i < 2 * PLSZ; i += 512) hP[i] = 0;
        // stage chunk 0 (steps 0..7): 3 rounds x 512 threads x 16B
#pragma unroll
        for (int rr = 0; rr < 3; ++rr)
            gload_lds16(XPB + (size_t)(bgid * 512) * 1536 + (rr * 512 + tid) * 8,
                        xch + (rr * 512 + tid) * 8);
        __syncthreads();   // drains vmcnt + publishes plane zeros

        for (int t = 0; t < 512; ++t) {
            const int r = t & 7;
            if (r < 3 && t < 504) {
                const unsigned short* src =
                    XPB + (size_t)(bgid * 512 + ((t >> 3) + 1) * 8) * 1536 + (r * 512 + tid) * 8;
                unsigned short* dst = xch + (((t >> 3) + 1) & 1) * 12288 + (r * 512 + tid) * 8;
                gload_lds16(src, dst);
            }
            const unsigned short* xc =
                xch + ((t >> 3) & 1) * 12288 + r * 1536 + (4 * wv + qq) * 16 + (cb & 3) * 4;
            uint2 u0 = *(const uint2*)(xc);
            uint2 u1 = *(const uint2*)(xc + 512);
            uint2 u2 = *(const uint2*)(xc + 1024);
            float pf0[4] = {bfhi(u0.x), bflo(u0.x), bfhi(u0.y), bflo(u0.y)};
            float pf1[4] = {bfhi(u1.x), bflo(u1.x), bfhi(u1.y), bflo(u1.y)};
            float pf2[4] = {bfhi(u2.x), bflo(u2.x), bfhi(u2.y), bflo(u2.y)};

            const unsigned short* HI = hP + (t & 1) * PLSZ;
            unsigned short* HIn = hP + ((t + 1) & 1) * PLSZ;

            f32x4 C0a = {0.f,0.f,0.f,0.f}, C1a = {0.f,0.f,0.f,0.f}, C2a = {0.f,0.f,0.f,0.f};
            f32x4 C0b = {0.f,0.f,0.f,0.f}, C1b = {0.f,0.f,0.f,0.f}, C2b = {0.f,0.f,0.f,0.f};
            {
                short8v B0 = *(const short8v*)(HI + cb * PLN + 0 * 32 + qq * 8);
                short8v B1 = *(const short8v*)(HI + cb * PLN + 1 * 32 + qq * 8);
                short8v B2 = *(const short8v*)(HI + cb * PLN + 2 * 32 + qq * 8);
                short8v B3 = *(const short8v*)(HI + cb * PLN + 3 * 32 + qq * 8);
                C0a = __builtin_amdgcn_mfma_f32_16x16x32_bf16(aH0[0], B0, C0a, 0, 0, 0);
                C1a = __builtin_amdgcn_mfma_f32_16x16x32_bf16(aH1[0], B0, C1a, 0, 0, 0);
                C2a = __builtin_amdgcn_mfma_f32_16x16x32_bf16(aH2[0], B0, C2a, 0, 0, 0);
                C0b = __builtin_amdgcn_mfma_f32_16x16x32_bf16(aH0[1], B1, C0b, 0, 0, 0);
                C1b = __builtin_amdgcn_mfma_f32_16x16x32_bf16(aH1[1], B1, C1b, 0, 0, 0);
                C2b = __builtin_amdgcn_mfma_f32_16x16x32_bf16(aH2[1], B1, C2b, 0, 0, 0);
                C0a = __builtin_amdgcn_mfma_f32_16x16x32_bf16(aH0[2], B2, C0a, 0, 0, 0);
                C1a = __builtin_amdgcn_mfma_f32_16x16x32_bf16(aH1[2], B2, C1a, 0, 0, 0);
                C2a = __builtin_amdgcn_mfma_f32_16x16x32_bf16(aH2[2], B2, C2a, 0, 0, 0);
                C0b = __builtin_amdgcn_mfma_f32_16x16x32_bf16(aH0[3], B3, C0b, 0, 0, 0);
                C1b = __builtin_amdgcn_mfma_f32_16x16x32_bf16(aH1[3], B3, C1b, 0, 0, 0);
                C2b = __builtin_amdgcn_mfma_f32_16x16x32_bf16(aH2[3], B3, C2b, 0, 0, 0);
            }
            float hnew[4];
#pragma unroll
            for (int i = 0; i < 4; ++i) {
                float pr = (C0a[i] + C0b[i]) + pf0[i];
                float pz = (C1a[i] + C1b[i]) + pf1[i];
                float rr2 = __builtin_amdgcn_rcpf(1.f + __expf(-pr));
                float z = __builtin_amdgcn_rcpf(1.f + __expf(-pz));
                float hn = (C2a[i] + C2b[i]) + bhn[i];
                float npre = fmaf(rr2, hn, pf2[i]);
                float e2 = __expf(-2.f * fabsf(npre));
                float n = copysignf((1.f - e2) * __builtin_amdgcn_rcpf(1.f + e2), npre);
                float hv = fmaf(z, hold[i] - n, n);
                hold[i] = hv;
                hnew[i] = hv;
            }
            if (cb < 4) {
                *(float4*)hp = make_float4(hnew[0], hnew[1], hnew[2], hnew[3]);
                uint2 hw;
                hw.x = (unsigned)f2bf(hnew[0]) | ((unsigned)f2bf(hnew[1]) << 16);
                hw.y = (unsigned)f2bf(hnew[2]) | ((unsigned)f2bf(hnew[3]) << 16);
                *(uint2*)(HIn + cb * PLN + 16 * wv + 4 * qq) = hw;
            }
            hp += 128;
            if (r == 7) wait_vm0();
            barrier_lgkm();
        }
    } else {
        // ---------------- beta scan, batches 4*bq .. 4*bq+3 ----------------
        const int bq = bgid - 4;
        float* bhL = (float*)smem;                                  // [4][512]  8192 B
        int*   poT = (int*)(smem + 8192);                           // [512][4]  8192 B
        unsigned short* h1P = (unsigned short*)(smem + 16384);      // PLSZ      4368 B
        float* redT = (float*)(smem + 20752);                       // [4][8]     128 B
        unsigned short* pch = (unsigned short*)(smem + 20880);      // 2 x 4096 ushorts
        const unsigned short* P1B = (const unsigned short*)ws + OFF_P1B_U;
        const int* POg = (const int*)(ws + OFF_PO);

        short8v aH[4];
#pragma unroll
        for (int kf = 0; kf < 4; ++kf) {
            short8v hi;
#pragma unroll
            for (int e = 0; e < 8; ++e)
                hi[e] = (short)f2bf(m2W2[(kf * 32 + qq * 8 + e) * 128 + 16 * wv + cb]);
            aH[kf] = hi;
        }
        float w3C[4], b2C[4];
        *(float4*)w3C = *(const float4*)&m2W3[16 * wv + 4 * qq];
        *(float4*)b2C = *(const float4*)&m2b2[16 * wv + 4 * qq];
        const float b3v = m2b3[0];

        const bool pa = (tid < 128);
        const int bb2 = tid & 3, j4 = (tid >> 2) & 31;
        float wvb[4] = {0.f, 0.f, 0.f, 0.f};
        if (pa) *(float4*)wvb = *(const float4*)&(ws + OFF_WVB)[j4 * 4];
        float btap = 0.f;

        for (int i = tid; i < 2048; i += 512)
            poT[i] = POg[(i >> 2) * 16 + 4 * bq + (i & 3)];
        for (int i = tid; i < PLSZ; i += 512) h1P[i] = 0;
        // stage chunk 0 (steps 0..7): wave w -> step w
        gload_lds16(P1B + (size_t)(wv * 16 + 4 * bq) * 128 + l * 8,
                    pch + wv * 512 + l * 8);
        __syncthreads();

        for (int t = 0; t < 512; ++t) {
            const int r = t & 7;
            // phase A: finalize beta(t-1), compute h1(t)
            if (pa) {
                if (t > 0) {
                    float4 ra = *(const float4*)&redT[bb2 * 8];
                    float4 rb = *(const float4*)&redT[bb2 * 8 + 4];
                    btap = ((ra.x + ra.y) + (ra.z + ra.w)) +
                           ((rb.x + rb.y) + (rb.z + rb.w)) + b3v;
                    if (j4 == 0) bhL[bb2 * 512 + (t - 1)] = btap;
                }
                int po = poT[t * 4 + bb2];
                float bp = (po == t - 1) ? btap : ((po >= 0) ? bhL[bb2 * 512 + po] : 0.f);
                const unsigned short* pc =
                    pch + ((t >> 3) & 1) * 4096 + r * 512 + bb2 * 128 + j4 * 4;
                uint2 u = *(const uint2*)pc;
                float h0 = fmaxf(0.f, fmaf(bp, wvb[0], bfhi(u.x)));
                float h1 = fmaxf(0.f, fmaf(bp, wvb[1], bflo(u.x)));
                float h2 = fmaxf(0.f, fmaf(bp, wvb[2], bfhi(u.y)));
                float h3 = fmaxf(0.f, fmaf(bp, wvb[3], bflo(u.y)));
                uint2 hw;
                hw.x = (unsigned)f2bf(h0) | ((unsigned)f2bf(h1) << 16);
                hw.y = (unsigned)f2bf(h2) | ((unsigned)f2bf(h3) << 16);
                *(uint2*)(h1P + bb2 * PLN + j4 * 4) = hw;
            }
            // stage next chunk (one round, at window start)
            if (r == 0 && t < 504) {
                const unsigned short* src =
                    P1B + (size_t)((t + 8 + wv) * 16 + 4 * bq) * 128 + l * 8;
                unsigned short* dst = pch + (((t >> 3) + 1) & 1) * 4096 + wv * 512 + l * 8;
                gload_lds16(src, dst);
            }
            barrier_lgkm();   // barrier 1: planes ready

            f32x4 Ca = {0.f, 0.f, 0.f, 0.f}, Cb = {0.f, 0.f, 0.f, 0.f};
            {
                short8v B0 = *(const short8v*)(h1P + cb * PLN + 0 * 32 + qq * 8);
                short8v B1 = *(const short8v*)(h1P + cb * PLN + 1 * 32 + qq * 8);
                short8v B2 = *(const short8v*)(h1P + cb * PLN + 2 * 32 + qq * 8);
                short8v B3 = *(const short8v*)(h1P + cb * PLN + 3 * 32 + qq * 8);
                Ca = __builtin_amdgcn_mfma_f32_16x16x32_bf16(aH[0], B0, Ca, 0, 0, 0);
                Cb = __builtin_amdgcn_mfma_f32_16x16x32_bf16(aH[1], B1, Cb, 0, 0, 0);
                Ca = __builtin_amdgcn_mfma_f32_16x16x32_bf16(aH[2], B2, Ca, 0, 0, 0);
                Cb = __builtin_amdgcn_mfma_f32_16x16x32_bf16(aH[3], B3, Cb, 0, 0, 0);
            }
            float part = 0.f;
#pragma unroll
            for (int i = 0; i < 4; ++i)
                part = fmaf(fmaxf(0.f, (Ca[i] + Cb[i]) + b2C[i]), w3C[i], part);
            part += __shfl_xor(part, 16);
            part += __shfl_xor(part, 32);
            if (qq == 0 && cb < 4) redT[cb * 8 + wv] = part;
            if (r == 7) wait_vm0();
            barrier_lgkm();   // barrier 2: redT ready
        }
        if (pa) {
            float4 ra = *(const float4*)&redT[bb2 * 8];
            float4 rb = *(const float4*)&redT[bb2 * 8 + 4];
            float bta = ((ra.x + ra.y) + (ra.z + ra.w)) +
                        ((rb.x + rb.y) + (rb.z + rb.w)) + b3v;
            if (j4 == 0) bhL[bb2 * 512 + 511] = bta;
        }
        __syncthreads();
        for (int i = tid; i < 2048; i += 512)
            beta_out[(4 * bq + (i >> 9)) * 512 + (i & 511)] = bhL[i];
    }
}

// ============ K2b: dense C fill (zeros + latest-occurrence betas) ============
__global__ __launch_bounds__(256) void k2b_fill(
    const int* __restrict__ c_seq, const float* __restrict__ beta_in,
    float* __restrict__ C_out)
{
    __shared__ int   scs[Sq];
    __shared__ float sbt[Sq];
    const int bid = blockIdx.x, tid = threadIdx.x;
    const int b = bid / 40, rem = bid % 40;
    const int chunk = rem >> 2, q = rem & 3;

    for (int i = tid; i < Sq; i += 256) {
        scs[i] = c_seq[b * Sq + i];
        sbt[i] = beta_in[b * Sq + i];
    }
    __syncthreads();

    const int c0 = chunk * 1024 + tid * 4;
    if (c0 >= NCq) return;

    float cur0 = 0.f, cur1 = 0.f, cur2 = 0.f, cur3 = 0.f;
    const int tlo = q * 128, thi = tlo + 128;
    float* base = C_out + (size_t)b * Sq * NCq + c0;

    for (int t = 0; t < tlo; ++t) {
        int ct = scs[t] - c0; float bv = sbt[t];
        cur0 = (ct == 0) ? bv : cur0;
        cur1 = (ct == 1) ? bv : cur1;
        cur2 = (ct == 2) ? bv : cur2;
        cur3 = (ct == 3) ? bv : cur3;
    }
    for (int t = tlo; t < thi; ++t) {
        int ct = scs[t] - c0; float bv = sbt[t];
        cur0 = (ct == 0) ? bv : cur0;
        cur1 = (ct == 1) ? bv : cur1;
        cur2 = (ct == 2) ? bv : cur2;
        cur3 = (ct == 3) ? bv : cur3;
        *(float4*)(base + (size_t)t * NCq) = make_float4(cur0, cur1, cur2, cur3);
    }
}

// ============ K3: alpha = mlp1(h_seq) ============
__global__ __launch_bounds__(256) void k3_alpha(
    const float* __restrict__ hseq,
    const float* __restrict__ W1, const float* __restrict__ b1,
    const float* __restrict__ W2, const float* __restrict__ b2,
    const float* __restrict__ W3, const float* __restrict__ b3,
    float* __restrict__ alpha_out)
{
    __shared__ float Hs[32 * 128];
    __shared__ float T1[32 * 128];
    __shared__ float red[4][16];
    const int blk = blockIdx.x, tid = threadIdx.x;
    const int row0 = blk * 32;

    for (int e = tid; e < 1024; e += 256) {
        int r = e >> 5, q = e & 31;
        *(float4*)&Hs[r * 128 + 4 * q] =
            *(const float4*)&hseq[(size_t)(row0 + r) * 128 + 4 * q];
    }
    __syncthreads();

    const int j = tid & 127, rh = tid >> 7;
    const float b1j = b1[j], b2j = b2[j], w3j = W3[j];
    float acc[16];
#pragma unroll
    for (int r = 0; r < 16; ++r) acc[r] = b1j;
    for (int k = 0; k < 128; ++k) {
        float w = W1[k * 128 + j];
#pragma unroll
        for (int r = 0; r < 16; ++r)
            acc[r] = fmaf(Hs[(rh * 16 + r) * 128 + k], w, acc[r]);
    }
#pragma unroll
    for (int r = 0; r < 16; ++r) {
        acc[r] = fmaxf(acc[r], 0.f);
        T1[(rh * 16 + r) * 128 + j] = acc[r];
    }
    __syncthreads();
    float acc2[16];
#pragma unroll
    for (int r = 0; r < 16; ++r) acc2[r] = b2j;
    for (int k = 0; k < 128; ++k) {
        float w = W2[k * 128 + j];
#pragma unroll
        for (int r = 0; r < 16; ++r)
            acc2[r] = fmaf(T1[(rh * 16 + r) * 128 + k], w, acc2[r]);
    }
#pragma unroll
    for (int r = 0; r < 16; ++r) {
        float p = fmaxf(acc2[r], 0.f) * w3j;
#pragma unroll
        for (int off = 1; off < 64; off <<= 1) p += __shfl_xor(p, off);
        if ((tid & 63) == 0) red[tid >> 6][r] = p;
    }
    __syncthreads();
    if (tid < 32) {
        int rr = tid & 15, g = tid >> 4;
        alpha_out[row0 + g * 16 + rr] = red[2 * g][rr] + red[2 * g + 1][rr] + b3[0];
    }
}

extern "C" void kernel_launch(void* const* d_in, const int* in_sizes, int n_in,
                              void* d_out, int out_size, void* d_ws, size_t ws_size,
                              hipStream_t stream) {
    const int*   c_seq = (const int*)d_in[0];
    const int*   d_seq = (const int*)d_in[1];
    const float* r_seq = (const float*)d_in[2];
    const float* D1_w  = (const float*)d_in[3];
    const float* D2_w  = (const float*)d_in[4];
    const float* v_r   = (const float*)d_in[5];
    const float* v_b   = (const float*)d_in[6];
    const float* W_ih  = (const float*)d_in[7];
    const float* W_hh  = (const float*)d_in[8];
    const float* b_ih  = (const float*)d_in[9];
    const float* b_hh  = (const float*)d_in[10];
    const float* m1W1  = (const float*)d_in[11];
    const float* m1b1  = (const float*)d_in[12];
    const float* m1W2  = (const float*)d_in[13];
    const float* m1b2  = (const float*)d_in[14];
    const float* m1W3  = (const float*)d_in[15];
    const float* m1b3  = (const float*)d_in[16];
    const float* m2W1  = (const float*)d_in[17];
    const float* m2b1  = (const float*)d_in[18];
    const float* m2W2  = (const float*)d_in[19];
    const float* m2b2  = (const float*)d_in[20];
    const float* m2W3  = (const float*)d_in[21];
    const float* m2b3  = (const float*)d_in[22];

    float* out   = (float*)d_out;
    float* alpha = out;                 // [16*512]
    float* beta  = out + 8192;          // [16*512]
    float* gamma = out + 16384;         // [16*512]
    float* hseq  = out + 24576;         // [16*512*128]
    float* Cseq  = out + 1073152;       // [16*512*10000]
    float* ws    = (float*)d_ws;

    hipLaunchKernelGGL(k0_prep, dim3(161), dim3(256), 0, stream,
                       c_seq, d_seq, D1_w, W_ih, v_r, v_b, m2W1, ws, gamma);
    hipLaunchKernelGGL(k1_gemm, dim3(1024), dim3(256), 0, stream,
                       d_seq, D2_w, m2W1, b_ih, b_hh, r_seq, m2b1, ws);
    hipLaunchKernelGGL(k2_scan, dim3(8), dim3(512), 0, stream,
                       W_hh, b_hh, m2W2, m2b2, m2W3, m2b3, ws, hseq, beta);
    hipLaunchKernelGGL(k2b_fill, dim3(640), dim3(256), 0, stream,
                       c_seq, beta, Cseq);
    hipLaunchKernelGGL(k3_alpha, dim3(256), dim3(256), 0, stream,
                       hseq, m1W1, m1b1, m1W2, m1b2, m1W3, m1b3, alpha);
}

// Round 10
// 618.789 us; speedup vs baseline: 1.8874x; 1.0187x over previous
//
#include <hip/hip_runtime.h>

#define Bq   16
#define Sq   512
#define Vq   128
#define NCq  10000

typedef __attribute__((ext_vector_type(8))) short short8v;
typedef __attribute__((ext_vector_type(4))) float f32x4;

// ---- workspace layout (float offsets) ----
#define OFF_XPF    0u          // [4 bg][512 t][96 r4][4 b][4 e] f32 (biases + r*wvr folded)
#define OFF_P1F    3145728u    // [512 t][16 b][128 j] f32 (b1 + r*wvr1 folded)
#define OFF_WTIH   4194304u    // [128 k][384 g] W_ih[:, :V]^T
#define OFF_WVRIH  4243456u    // [384]
#define OFF_WVR1   4243840u    // [128]
#define OFF_WVB    4243968u    // [128]
#define OFF_PO     4244096u    // int [512 t][16 b]

#define PLN 136
#define PLSZ (16*PLN+8)

__device__ __forceinline__ unsigned cvt_pk_bf16(float a, float b) {
    unsigned r;
    asm("v_cvt_pk_bf16_f32 %0, %1, %2" : "=v"(r) : "v"(a), "v"(b));
    return r;
}
__device__ __forceinline__ void barrier_lgkm() {
    asm volatile("s_waitcnt lgkmcnt(0)" ::: "memory");
    __builtin_amdgcn_sched_barrier(0);
    __builtin_amdgcn_s_barrier();
    __builtin_amdgcn_sched_barrier(0);
}
__device__ __forceinline__ void wait_vm4() {
    asm volatile("s_waitcnt vmcnt(4)" ::: "memory");
    __builtin_amdgcn_sched_barrier(0);
}
__device__ __forceinline__ void wait_vm2() {
    asm volatile("s_waitcnt vmcnt(2)" ::: "memory");
    __builtin_amdgcn_sched_barrier(0);
}
__device__ __forceinline__ void gload_lds16(const void* g, void* l) {
    __builtin_amdgcn_global_load_lds(
        (const __attribute__((address_space(1))) unsigned int*)g,
        (__attribute__((address_space(3))) unsigned int*)l, 16, 0, 0);
}

// ============ K0: transpose, small vectors, prev-occurrence, gamma ============
__global__ __launch_bounds__(256) void k0_prep(
    const int* __restrict__ c_seq, const int* __restrict__ d_seq,
    const float* __restrict__ D1_w,
    const float* __restrict__ W_ih,
    const float* __restrict__ v_r, const float* __restrict__ v_beta,
    const float* __restrict__ m2W1,
    float* __restrict__ ws, float* __restrict__ gamma_out)
{
    const int blk = blockIdx.x, tid = threadIdx.x;

    if (blk < 128) {
        float* WTIH = ws + OFF_WTIH;
        int base = blk * 384;
        for (int i = tid; i < 384; i += 256) {
            int e = base + i;
            int k = e / 384, g = e % 384;
            WTIH[e] = W_ih[g * 256 + k];
        }
    } else if (blk == 128) {
        float* WVRIH = ws + OFF_WVRIH;
        float* WVR1  = ws + OFF_WVR1;
        float* WVB   = ws + OFF_WVB;
        for (int g = tid; g < 384; g += 256) {
            float a = 0.f;
            for (int k = 0; k < 128; ++k) a = fmaf(v_r[k], W_ih[g * 256 + 128 + k], a);
            WVRIH[g] = a;
        }
        if (tid < 128) {
            float a = 0.f, b = 0.f;
            for (int k = 0; k < 128; ++k) {
                a = fmaf(v_r[k],    m2W1[(256 + k) * 128 + tid], a);
                b = fmaf(v_beta[k], m2W1[k * 128 + tid],         b);
            }
            WVR1[tid] = a; WVB[tid] = b;
        }
    } else if (blk < 145) {
        const int b = blk - 129;
        __shared__ int cs[Sq];
        for (int i = tid; i < Sq; i += 256) cs[i] = c_seq[b * Sq + i];
        __syncthreads();
        int* PO = (int*)(ws + OFF_PO);
        for (int t = tid; t < Sq; t += 256) {
            int c = cs[t];
            int po = -1;
            for (int u = t - 1; u >= 0; --u) if (cs[u] == c) { po = u; break; }
            PO[t * 16 + b] = po;
        }
    } else {
        const int b = blk - 145;
        for (int s = tid; s < Sq; s += 256)
            gamma_out[b * Sq + s] = D1_w[d_seq[b * Sq + s]];
    }
}

// ============ K1: batched GEMM -> XPF (f32) | P1F (f32), biases folded ============
__global__ __launch_bounds__(256) void k1_gemm(
    const int* __restrict__ d_seq, const float* __restrict__ D2_w,
    const float* __restrict__ m2W1,
    const float* __restrict__ b_ih, const float* __restrict__ b_hh,
    const float* __restrict__ r_seq, const float* __restrict__ m2b1,
    float* __restrict__ ws)
{
    __shared__ float As[64 * 128];
    __shared__ float Bs[128 * 64];
    const int blk = blockIdx.x, tid = threadIdx.x;
    const int nc = blk & 7;
    const int m0 = (blk >> 3) * 64;
    const float* WTIH = ws + OFF_WTIH;

    const float4* D2v = (const float4*)D2_w;
    for (int e = tid; e < 2048; e += 256) {
        int r = e >> 5, q = e & 31;
        int d = d_seq[m0 + r];
        *(float4*)&As[r * 128 + 4 * q] = D2v[d * 32 + q];
    }
    for (int e = tid; e < 2048; e += 256) {
        int k = e >> 4, q = e & 15;
        float4 v;
        if (nc < 6) v = *(const float4*)&WTIH[k * 384 + nc * 64 + 4 * q];
        else        v = *(const float4*)&m2W1[(128 + k) * 128 + (nc - 6) * 64 + 4 * q];
        *(float4*)&Bs[k * 64 + 4 * q] = v;
    }
    __syncthreads();

    const int tx = tid & 15, ty = tid >> 4;
    const int c0 = 4 * tx, r0 = 4 * ty;
    float acc[4][4];
#pragma unroll
    for (int i = 0; i < 4; ++i)
#pragma unroll
        for (int j = 0; j < 4; ++j) acc[i][j] = 0.f;

    for (int k = 0; k < 128; ++k) {
        float4 bv = *(const float4*)&Bs[k * 64 + c0];
#pragma unroll
        for (int i = 0; i < 4; ++i) {
            float a = As[(r0 + i) * 128 + k];
            acc[i][0] = fmaf(a, bv.x, acc[i][0]);
            acc[i][1] = fmaf(a, bv.y, acc[i][1]);
            acc[i][2] = fmaf(a, bv.z, acc[i][2]);
            acc[i][3] = fmaf(a, bv.w, acc[i][3]);
        }
    }

    float rsv[4];
#pragma unroll
    for (int i = 0; i < 4; ++i) rsv[i] = r_seq[m0 + r0 + i];

    if (nc < 6) {
        const int grow0 = nc * 64 + c0;
        float4 bi  = *(const float4*)&b_ih[grow0];
        float4 wv4 = *(const float4*)&(ws + OFF_WVRIH)[grow0];
        float4 bh4 = make_float4(0.f, 0.f, 0.f, 0.f);
        if (nc < 4) bh4 = *(const float4*)&b_hh[grow0];   // r,z gates get b_hh folded
        float* XPF = ws + OFF_XPF;
        const int r4 = grow0 >> 2;
#pragma unroll
        for (int i = 0; i < 4; ++i) {
            int row = m0 + r0 + i;
            int t = row & 511, bb = row >> 9;
            float4 v;
            v.x = acc[i][0] + bi.x + bh4.x + rsv[i] * wv4.x;
            v.y = acc[i][1] + bi.y + bh4.y + rsv[i] * wv4.y;
            v.z = acc[i][2] + bi.z + bh4.z + rsv[i] * wv4.z;
            v.w = acc[i][3] + bi.w + bh4.w + rsv[i] * wv4.w;
            *(float4*)&XPF[((size_t)((bb >> 2) * 512 + t)) * 1536 + r4 * 16 + (bb & 3) * 4] = v;
        }
    } else {
        const int j0 = (nc - 6) * 64 + c0;
        float4 b1v = *(const float4*)&m2b1[j0];
        float4 wr1 = *(const float4*)&(ws + OFF_WVR1)[j0];
        float* P1F = ws + OFF_P1F;
#pragma unroll
        for (int i = 0; i < 4; ++i) {
            int row = m0 + r0 + i;
            int t = row & 511, bb = row >> 9;
            float4 v;
            v.x = acc[i][0] + b1v.x + rsv[i] * wr1.x;
            v.y = acc[i][1] + b1v.y + rsv[i] * wr1.y;
            v.z = acc[i][2] + b1v.z + rsv[i] * wr1.z;
            v.w = acc[i][3] + b1v.w + rsv[i] * wr1.w;
            *(float4*)&P1F[((size_t)(t * 16 + bb)) * 128 + j0] = v;
        }
    }
}

// ============ K2: 8 blocks. blk 0..3: GRU (4 batches). blk 4..7: beta (4 batches) ============
// f32 XP/PRE1 staged via 4-slot LDS ring (1 gload/step, counted vmcnt, never drained to 0)
__global__ __launch_bounds__(512, 1) void k2_scan(
    const float* __restrict__ W_hh, const float* __restrict__ b_hh,
    const float* __restrict__ m2W2, const float* __restrict__ m2b2,
    const float* __restrict__ m2W3, const float* __restrict__ m2b3,
    float* __restrict__ ws,
    float* __restrict__ hseq_out, float* __restrict__ beta_out)
{
    __shared__ __align__(16) unsigned char smem[41504];
    const int tid = threadIdx.x;
    const int l = tid & 63, wv = tid >> 6;
    const int qq = l >> 4, cb = l & 15;
    const int bgid = blockIdx.x;

    if (bgid < 4) {
        // ---------------- GRU, batches 4*bgid .. 4*bgid+3 ----------------
        unsigned short* hP  = (unsigned short*)smem;                // [2][PLSZ]
        unsigned char*  xsl = smem + 8736;                          // 4 slots x 8192 B
        const float* XPF = ws + OFF_XPF;

        short8v aH0[4], aH1[4], aH2[4];
#pragma unroll
        for (int kf = 0; kf < 4; ++kf) {
            const int kb = kf * 32 + qq * 8;
            const float* w0 = W_hh + (0 * 128 + 16 * wv + cb) * 128 + kb;
            const float* w1 = W_hh + (1 * 128 + 16 * wv + cb) * 128 + kb;
            const float* w2 = W_hh + (2 * 128 + 16 * wv + cb) * 128 + kb;
            short8v h0, h1, h2;
#pragma unroll
            for (int e = 0; e < 8; ++e) {
                unsigned u0 = __builtin_bit_cast(unsigned, w0[e]);
                unsigned u1 = __builtin_bit_cast(unsigned, w1[e]);
                unsigned u2 = __builtin_bit_cast(unsigned, w2[e]);
                h0[e] = (short)((u0 + 0x7fffu + ((u0 >> 16) & 1u)) >> 16);
                h1[e] = (short)((u1 + 0x7fffu + ((u1 >> 16) & 1u)) >> 16);
                h2[e] = (short)((u2 + 0x7fffu + ((u2 >> 16) & 1u)) >> 16);
            }
            aH0[kf] = h0; aH1[kf] = h1; aH2[kf] = h2;
        }
        f32x4 bhn4;
        {
            float4 t4 = *(const float4*)&b_hh[256 + 16 * wv + 4 * qq];
            bhn4[0] = t4.x; bhn4[1] = t4.y; bhn4[2] = t4.z; bhn4[3] = t4.w;
        }

        float* hp = hseq_out + ((size_t)((bgid * 4 + (cb & 3)) * 512)) * 128 + 16 * wv + 4 * qq;
        float hold[4] = {0.f, 0.f, 0.f, 0.f};
        for (int i = tid; i < 2 * PLSZ; i += 512) hP[i] = 0;
#pragma unroll
        for (int s = 0; s < 3; ++s)
            gload_lds16(XPF + ((size_t)(bgid * 512 + s)) * 1536 + tid * 4,
                        xsl + s * 8192 + tid * 16);
        __syncthreads();   // drains prologue vmcnt + publishes plane zeros

        const float NL2E = -1.44269504f, L2E2 = 2.88539008f;
        for (int t = 0; t < 512; ++t) {
            if (t < 509)
                gload_lds16(XPF + ((size_t)(bgid * 512 + t + 3)) * 1536 + tid * 4,
                            xsl + ((t + 3) & 3) * 8192 + tid * 16);

            const float* xc = (const float*)(xsl + (t & 3) * 8192) +
                              (4 * wv + qq) * 16 + (cb & 3) * 4;
            f32x4 px0 = *(const f32x4*)(xc);
            f32x4 px1 = *(const f32x4*)(xc + 512);
            f32x4 px2 = *(const f32x4*)(xc + 1024);

            const unsigned short* HI = hP + (t & 1) * PLSZ;
            unsigned short* HIn = hP + ((t + 1) & 1) * PLSZ;

            f32x4 C0a = px0, C1a = px1, C2a = bhn4;
            f32x4 C0b = {0.f,0.f,0.f,0.f}, C1b = {0.f,0.f,0.f,0.f}, C2b = {0.f,0.f,0.f,0.f};
            {
                short8v B0 = *(const short8v*)(HI + cb * PLN + 0 * 32 + qq * 8);
                short8v B1 = *(const short8v*)(HI + cb * PLN + 1 * 32 + qq * 8);
                short8v B2 = *(const short8v*)(HI + cb * PLN + 2 * 32 + qq * 8);
                short8v B3 = *(const short8v*)(HI + cb * PLN + 3 * 32 + qq * 8);
                C0a = __builtin_amdgcn_mfma_f32_16x16x32_bf16(aH0[0], B0, C0a, 0, 0, 0);
                C1a = __builtin_amdgcn_mfma_f32_16x16x32_bf16(aH1[0], B0, C1a, 0, 0, 0);
                C2a = __builtin_amdgcn_mfma_f32_16x16x32_bf16(aH2[0], B0, C2a, 0, 0, 0);
                C0b = __builtin_amdgcn_mfma_f32_16x16x32_bf16(aH0[1], B1, C0b, 0, 0, 0);
                C1b = __builtin_amdgcn_mfma_f32_16x16x32_bf16(aH1[1], B1, C1b, 0, 0, 0);
                C2b = __builtin_amdgcn_mfma_f32_16x16x32_bf16(aH2[1], B1, C2b, 0, 0, 0);
                C0a = __builtin_amdgcn_mfma_f32_16x16x32_bf16(aH0[2], B2, C0a, 0, 0, 0);
                C1a = __builtin_amdgcn_mfma_f32_16x16x32_bf16(aH1[2], B2, C1a, 0, 0, 0);
                C2a = __builtin_amdgcn_mfma_f32_16x16x32_bf16(aH2[2], B2, C2a, 0, 0, 0);
                C0b = __builtin_amdgcn_mfma_f32_16x16x32_bf16(aH0[3], B3, C0b, 0, 0, 0);
                C1b = __builtin_amdgcn_mfma_f32_16x16x32_bf16(aH1[3], B3, C1b, 0, 0, 0);
                C2b = __builtin_amdgcn_mfma_f32_16x16x32_bf16(aH2[3], B3, C2b, 0, 0, 0);
            }
            float hnew[4];
#pragma unroll
            for (int i = 0; i < 4; ++i) {
                float pr = C0a[i] + C0b[i];
                float pz = C1a[i] + C1b[i];
                float hn = C2a[i] + C2b[i];
                float r = __builtin_amdgcn_rcpf(1.f + __builtin_amdgcn_exp2f(pr * NL2E));
                float z = __builtin_amdgcn_rcpf(1.f + __builtin_amdgcn_exp2f(pz * NL2E));
                float npre = fmaf(r, hn, px2[i]);
                float n = fmaf(-2.f, __builtin_amdgcn_rcpf(1.f + __builtin_amdgcn_exp2f(npre * L2E2)), 1.f);
                float hv = fmaf(z, hold[i] - n, n);
                hold[i] = hv;
                hnew[i] = hv;
            }
            if (cb < 4) {
                *(float4*)hp = make_float4(hnew[0], hnew[1], hnew[2], hnew[3]);
                uint2 hw;
                hw.x = cvt_pk_bf16(hnew[0], hnew[1]);
                hw.y = cvt_pk_bf16(hnew[2], hnew[3]);
                *(uint2*)(HIn + cb * PLN + 16 * wv + 4 * qq) = hw;
            }
            hp += 128;
            wait_vm4();
            barrier_lgkm();
        }
    } else {
        // ---------------- beta scan, batches 4*bq .. 4*bq+3 ----------------
        const int bq = bgid - 4;
        float* bhL = (float*)smem;                                  // [4][512]  8192 B
        unsigned short* h1P = (unsigned short*)(smem + 8192);       // PLSZ      4368 B
        float* redT = (float*)(smem + 12560);                       // [4][8]     128 B
        unsigned char* psl = smem + 12688;                          // 4 slots x 2048 B
        const float* P1F = ws + OFF_P1F;
        const int* POg = (const int*)(ws + OFF_PO);

        short8v aH[4];
#pragma unroll
        for (int kf = 0; kf < 4; ++kf) {
            short8v hi;
#pragma unroll
            for (int e = 0; e < 8; ++e) {
                unsigned u = __builtin_bit_cast(unsigned,
                    m2W2[(kf * 32 + qq * 8 + e) * 128 + 16 * wv + cb]);
                hi[e] = (short)((u + 0x7fffu + ((u >> 16) & 1u)) >> 16);
            }
            aH[kf] = hi;
        }
        float w3C[4];
        f32x4 b2C4;
        *(float4*)w3C = *(const float4*)&m2W3[16 * wv + 4 * qq];
        {
            float4 t4 = *(const float4*)&m2b2[16 * wv + 4 * qq];
            b2C4[0] = t4.x; b2C4[1] = t4.y; b2C4[2] = t4.z; b2C4[3] = t4.w;
        }
        const float b3v = m2b3[0];

        const bool pa = (tid < 128);
        const int bb2 = tid & 3, j4 = (tid >> 2) & 31;
        float wvb[4] = {0.f, 0.f, 0.f, 0.f};
        int poCur = -1, poNxt = -1;
        float bpPre = 0.f, btap = 0.f;
        if (pa) {
            *(float4*)wvb = *(const float4*)&(ws + OFF_WVB)[j4 * 4];
            poCur = POg[0 * 16 + 4 * bq + bb2];
            poNxt = POg[1 * 16 + 4 * bq + bb2];
#pragma unroll
            for (int s = 0; s < 3; ++s)
                gload_lds16(P1F + ((size_t)(s * 16 + 4 * bq)) * 128 + tid * 4,
                            psl + s * 2048 + tid * 16);
        }
        for (int i = tid; i < PLSZ; i += 512) h1P[i] = 0;
        __syncthreads();

        for (int t = 0; t < 512; ++t) {
            // phase A: finalize beta(t-1), compute h1(t)
            if (pa) {
                if (t > 0) {
                    float4 ra = *(const float4*)&redT[bb2 * 8];
                    float4 rb = *(const float4*)&redT[bb2 * 8 + 4];
                    btap = ((ra.x + ra.y) + (ra.z + ra.w)) +
                           ((rb.x + rb.y) + (rb.z + rb.w)) + b3v;
                    if (j4 == 0) bhL[bb2 * 512 + (t - 1)] = btap;
                }
                int po = poCur;
                float bp = (po == t - 1) ? btap : bpPre;
                const float* pc = (const float*)(psl + (t & 3) * 2048) + bb2 * 128 + j4 * 4;
                f32x4 p1 = *(const f32x4*)pc;
                float h0 = fmaxf(0.f, fmaf(bp, wvb[0], p1[0]));
                float h1 = fmaxf(0.f, fmaf(bp, wvb[1], p1[1]));
                float h2 = fmaxf(0.f, fmaf(bp, wvb[2], p1[2]));
                float h3 = fmaxf(0.f, fmaf(bp, wvb[3], p1[3]));
                uint2 hw;
                hw.x = cvt_pk_bf16(h0, h1);
                hw.y = cvt_pk_bf16(h2, h3);
                *(uint2*)(h1P + bb2 * PLN + j4 * 4) = hw;
                if (t < 509)
                    gload_lds16(P1F + ((size_t)((t + 3) * 16 + 4 * bq)) * 128 + tid * 4,
                                psl + ((t + 3) & 3) * 2048 + tid * 16);
            }
            barrier_lgkm();   // barrier 1: planes ready

            if (pa) {
                bpPre = 0.f;
                if (poNxt >= 0 && poNxt < t) bpPre = bhL[bb2 * 512 + poNxt];
                poCur = poNxt;
                if (t < 510) poNxt = POg[(t + 2) * 16 + 4 * bq + bb2];
            }
            f32x4 Ca = b2C4, Cb = {0.f, 0.f, 0.f, 0.f};
            {
                short8v B0 = *(const short8v*)(h1P + cb * PLN + 0 * 32 + qq * 8);
                short8v B1 = *(const short8v*)(h1P + cb * PLN + 1 * 32 + qq * 8);
                short8v B2 = *(const short8v*)(h1P + cb * PLN + 2 * 32 + qq * 8);
                short8v B3 = *(const short8v*)(h1P + cb * PLN + 3 * 32 + qq * 8);
                Ca = __builtin_amdgcn_mfma_f32_16x16x32_bf16(aH[0], B0, Ca, 0, 0, 0);
                Cb = __builtin_amdgcn_mfma_f32_16x16x32_bf16(aH[1], B1, Cb, 0, 0, 0);
                Ca = __builtin_amdgcn_mfma_f32_16x16x32_bf16(aH[2], B2, Ca, 0, 0, 0);
                Cb = __builtin_amdgcn_mfma_f32_16x16x32_bf16(aH[3], B3, Cb, 0, 0, 0);
            }
            float part = 0.f;
#pragma unroll
            for (int i = 0; i < 4; ++i)
                part = fmaf(fmaxf(0.f, Ca[i] + Cb[i]), w3C[i], part);
            part += __shfl_xor(part, 16);
            part += __shfl_xor(part, 32);
            if (qq == 0 && cb < 4) redT[cb * 8 + wv] = part;
            wait_vm2();
            barrier_lgkm();   // barrier 2: redT ready
        }
        if (pa) {
            float4 ra = *(const float4*)&redT[bb2 * 8];
            float4 rb = *(const float4*)&redT[bb2 * 8 + 4];
            float bta = ((ra.x + ra.y) + (ra.z + ra.w)) +
                        ((rb.x + rb.y) + (rb.z + rb.w)) + b3v;
            if (j4 == 0) bhL[bb2 * 512 + 511] = bta;
        }
        __syncthreads();
        for (int i = tid; i < 2048; i += 512)
            beta_out[(4 * bq + (i >> 9)) * 512 + (i & 511)] = bhL[i];
    }
}

// ============ K2b: dense C fill (zeros + latest-occurrence betas) ============
__global__ __launch_bounds__(256) void k2b_fill(
    const int* __restrict__ c_seq, const float* __restrict__ beta_in,
    float* __restrict__ C_out)
{
    __shared__ int   scs[Sq];
    __shared__ float sbt[Sq];
    const int bid = blockIdx.x, tid = threadIdx.x;
    const int b = bid / 40, rem = bid % 40;
    const int chunk = rem >> 2, q = rem & 3;

    for (int i = tid; i < Sq; i += 256) {
        scs[i] = c_seq[b * Sq + i];
        sbt[i] = beta_in[b * Sq + i];
    }
    __syncthreads();

    const int c0 = chunk * 1024 + tid * 4;
    if (c0 >= NCq) return;

    float cur0 = 0.f, cur1 = 0.f, cur2 = 0.f, cur3 = 0.f;
    const int tlo = q * 128, thi = tlo + 128;
    float* base = C_out + (size_t)b * Sq * NCq + c0;

    for (int t = 0; t < tlo; ++t) {
        int ct = scs[t] - c0; float bv = sbt[t];
        cur0 = (ct == 0) ? bv : cur0;
        cur1 = (ct == 1) ? bv : cur1;
        cur2 = (ct == 2) ? bv : cur2;
        cur3 = (ct == 3) ? bv : cur3;
    }
    for (int t = tlo; t < thi; ++t) {
        int ct = scs[t] - c0; float bv = sbt[t];
        cur0 = (ct == 0) ? bv : cur0;
        cur1 = (ct == 1) ? bv : cur1;
        cur2 = (ct == 2) ? bv : cur2;
        cur3 = (ct == 3) ? bv : cur3;
        *(float4*)(base + (size_t)t * NCq) = make_float4(cur0, cur1, cur2, cur3);
    }
}

// ============ K3: alpha = mlp1(h_seq) ============
__global__ __launch_bounds__(256) void k3_alpha(
    const float* __restrict__ hseq,
    const float* __restrict__ W1, const float* __restrict__ b1,
    const float* __restrict__ W2, const float* __restrict__ b2,
    const float* __restrict__ W3, const float* __restrict__ b3,
    float* __restrict__ alpha_out)
{
    __shared__ float Hs[32 * 128];
    __shared__ float T1[32 * 128];
    __shared__ float red[4][16];
    const int blk = blockIdx.x, tid = threadIdx.x;
    const int row0 = blk * 32;

    for (int e = tid; e < 1024; e += 256) {
        int r = e >> 5, q = e & 31;
        *(float4*)&Hs[r * 128 + 4 * q] =
            *(const float4*)&hseq[(size_t)(row0 + r) * 128 + 4 * q];
    }
    __syncthreads();

    const int j = tid & 127, rh = tid >> 7;
    const float b1j = b1[j], b2j = b2[j], w3j = W3[j];
    float acc[16];
#pragma unroll
    for (int r = 0; r < 16; ++r) acc[r] = b1j;
    for (int k = 0; k < 128; ++k) {
        float w = W1[k * 128 + j];
#pragma unroll
        for (int r = 0; r < 16; ++r)
            acc[r] = fmaf(Hs[(rh * 16 + r) * 128 + k], w, acc[r]);
    }
#pragma unroll
    for (int r = 0; r < 16; ++r) {
        acc[r] = fmaxf(acc[r], 0.f);
        T1[(rh * 16 + r) * 128 + j] = acc[r];
    }
    __syncthreads();
    float acc2[16];
#pragma unroll
    for (int r = 0; r < 16; ++r) acc2[r] = b2j;
    for (int k = 0; k < 128; ++k) {
        float w = W2[k * 128 + j];
#pragma unroll
        for (int r = 0; r < 16; ++r)
            acc2[r] = fmaf(T1[(rh * 16 + r) * 128 + k], w, acc2[r]);
    }
#pragma unroll
    for (int r = 0; r < 16; ++r) {
        float p = fmaxf(acc2[r], 0.f) * w3j;
#pragma unroll
        for (int off = 1; off < 64; off <<= 1) p += __shfl_xor(p, off);
        if ((tid & 63) == 0) red[tid >> 6][r] = p;
    }
    __syncthreads();
    if (tid < 32) {
        int rr = tid & 15, g = tid >> 4;
        alpha_out[row0 + g * 16 + rr] = red[2 * g][rr] + red[2 * g + 1][rr] + b3[0];
    }
}

extern "C" void kernel_launch(void* const* d_in, const int* in_sizes, int n_in,
                              void* d_out, int out_size, void* d_ws, size_t ws_size,
                              hipStream_t stream) {
    const int*   c_seq = (const int*)d_in[0];
    const int*   d_seq = (const int*)d_in[1];
    const float* r_seq = (const float*)d_in[2];
    const float* D1_w  = (const float*)d_in[3];
    const float* D2_w  = (const float*)d_in[4];
    const float* v_r   = (const float*)d_in[5];
    const float* v_b   = (const float*)d_in[6];
    const float* W_ih  = (const float*)d_in[7];
    const float* W_hh  = (const float*)d_in[8];
    const float* b_ih  = (const float*)d_in[9];
    const float* b_hh  = (const float*)d_in[10];
    const float* m1W1  = (const float*)d_in[11];
    const float* m1b1  = (const float*)d_in[12];
    const float* m1W2  = (const float*)d_in[13];
    const float* m1b2  = (const float*)d_in[14];
    const float* m1W3  = (const float*)d_in[15];
    const float* m1b3  = (const float*)d_in[16];
    const float* m2W1  = (const float*)d_in[17];
    const float* m2b1  = (const float*)d_in[18];
    const float* m2W2  = (const float*)d_in[19];
    const float* m2b2  = (const float*)d_in[20];
    const float* m2W3  = (const float*)d_in[21];
    const float* m2b3  = (const float*)d_in[22];

    float* out   = (float*)d_out;
    float* alpha = out;                 // [16*512]
    float* beta  = out + 8192;          // [16*512]
    float* gamma = out + 16384;         // [16*512]
    float* hseq  = out + 24576;         // [16*512*128]
    float* Cseq  = out + 1073152;       // [16*512*10000]
    float* ws    = (float*)d_ws;

    hipLaunchKernelGGL(k0_prep, dim3(161), dim3(256), 0, stream,
                       c_seq, d_seq, D1_w, W_ih, v_r, v_b, m2W1, ws, gamma);
    hipLaunchKernelGGL(k1_gemm, dim3(1024), dim3(256), 0, stream,
                       d_seq, D2_w, m2W1, b_ih, b_hh, r_seq, m2b1, ws);
    hipLaunchKernelGGL(k2_scan, dim3(8), dim3(512), 0, stream,
                       W_hh, b_hh, m2W2, m2b2, m2W3, m2b3, ws, hseq, beta);
    hipLaunchKernelGGL(k2b_fill, dim3(640), dim3(256), 0, stream,
                       c_seq, beta, Cseq);
    hipLaunchKernelGGL(k3_alpha, dim3(256), dim3(256), 0, stream,
                       hseq, m1W1, m1b1, m1W2, m1b2, m1W3, m1b3, alpha);
}